// Round 2
// baseline (285.744 us; speedup 1.0000x reference)
//
#include <hip/hip_runtime.h>
#include <hip/hip_bf16.h>

#define DEV static __device__ __forceinline__

typedef __bf16 bf16x8 __attribute__((ext_vector_type(8)));
typedef unsigned short u16x8 __attribute__((ext_vector_type(8)));
typedef float f32x4 __attribute__((ext_vector_type(4)));

// ---------- helpers ----------

DEV unsigned short f2bf(float f) {
    unsigned u = __builtin_bit_cast(unsigned, f);
    u += 0x7FFFu + ((u >> 16) & 1u);          // RNE (finite inputs only)
    return (unsigned short)(u >> 16);
}

DEV float gelu_f(float x) {
    // tanh-approx gelu == x * sigmoid(1.5957691*(x + 0.044715 x^3)) (matches jax.nn.gelu)
    float u = x * (1.0f + 0.044715f * x * x);
    return x / (1.0f + __expf(-1.5957691216057308f * u));
}

DEV f32x4 mfma16(bf16x8 a, bf16x8 b, f32x4 c) {
    return __builtin_amdgcn_mfma_f32_16x16x32_bf16(a, b, c, 0, 0, 0);
}

// load 8 consecutive f32 (16B-aligned) -> bf16x8
DEV bf16x8 aload_f32(const float* p) {
    float4 x = *(const float4*)p;
    float4 y = *(const float4*)(p + 4);
    u16x8 s;
    s[0] = f2bf(x.x); s[1] = f2bf(x.y); s[2] = f2bf(x.z); s[3] = f2bf(x.w);
    s[4] = f2bf(y.x); s[5] = f2bf(y.y); s[6] = f2bf(y.z); s[7] = f2bf(y.w);
    return __builtin_bit_cast(bf16x8, s);
}

DEV bf16x8 uload(const unsigned short* p) {
    return __builtin_bit_cast(bf16x8, *(const u16x8*)p);
}

// B-fragment read from LDS WT[n][k] (stride 136 u16), col = n, koff = k start (mult of 8)
DEV bf16x8 bload(const unsigned short* WT, int col, int koff) {
    return __builtin_bit_cast(bf16x8, *(const u16x8*)(WT + col * 136 + koff));
}

// copy pre-transposed bf16 weight [128n][128k] from global into LDS WT[n*136+k]
DEV void stage_wt(unsigned short* WT, const unsigned short* src, int tid, int nthr) {
    for (int i = tid; i < 2048; i += nthr) {
        int n = i >> 4, k0 = (i & 15) << 3;
        *(u16x8*)(WT + n * 136 + k0) = *(const u16x8*)(src + n * 128 + k0);
    }
}

// ---------- weight pre-transpose: f32 [128k][128n] -> bf16 [128n][128k] ----------
// 22 matrices of 128x128: 0 smW1(V-half) 1 smW1(Z-half) 2 smW2 3 proj,
// then per layer l: 4+6l+{0:W1a,1:W1b,2:W1c,3:msgW2,4:ffnW1,5:ffnW2}
__global__ __launch_bounds__(256) void k_wconv(
    const float* __restrict__ smW1, const float* __restrict__ smW2,
    const float* __restrict__ projW, const float* __restrict__ msgW1,
    const float* __restrict__ msgW2, const float* __restrict__ ffnW1,
    const float* __restrict__ ffnW2, unsigned short* __restrict__ WTG)
{
    int m = blockIdx.x >> 3;
    int chunk = blockIdx.x & 7;
    const float* src;
    if (m == 0) src = smW1;
    else if (m == 1) src = smW1 + 16384;
    else if (m == 2) src = smW2;
    else if (m == 3) src = projW;
    else {
        int mm = m - 4; int l = mm / 6; int j = mm % 6;
        if (j < 3)      src = msgW1 + l * 49152 + j * 16384;
        else if (j == 3) src = msgW2 + l * 16384;
        else if (j == 4) src = ffnW1 + l * 16384;
        else             src = ffnW2 + l * 16384;
    }
    unsigned short* dst = WTG + m * 16384;
    int s0 = chunk * 2048 + threadIdx.x * 8;   // flat src index, k = s0>>7, n = s0&127
    int k = s0 >> 7, n = s0 & 127;
    float4 x = *(const float4*)(src + s0);
    float4 y = *(const float4*)(src + s0 + 4);
    dst[(n + 0) * 128 + k] = f2bf(x.x);
    dst[(n + 1) * 128 + k] = f2bf(x.y);
    dst[(n + 2) * 128 + k] = f2bf(x.z);
    dst[(n + 3) * 128 + k] = f2bf(x.w);
    dst[(n + 4) * 128 + k] = f2bf(y.x);
    dst[(n + 5) * 128 + k] = f2bf(y.y);
    dst[(n + 6) * 128 + k] = f2bf(y.z);
    dst[(n + 7) * 128 + k] = f2bf(y.w);
}

// ---------- E f32 [tok][30][128] -> bf16 padded [tok][32][128] (rows 30,31 = 0) ----------
__global__ __launch_bounds__(256) void k_econv(
    const float* __restrict__ E, unsigned short* __restrict__ Ebf)
{
    int i = blockIdx.x * 256 + threadIdx.x;     // 8192*32*16 threads
    int tok = i >> 9;
    int r = (i >> 4) & 31;
    int d8 = (i & 15) << 3;
    u16x8 s = {0, 0, 0, 0, 0, 0, 0, 0};
    if (r < 30) {
        const float* p = E + ((size_t)tok * 30 + r) * 128 + d8;
        float4 x = *(const float4*)p;
        float4 y = *(const float4*)(p + 4);
        s[0] = f2bf(x.x); s[1] = f2bf(x.y); s[2] = f2bf(x.z); s[3] = f2bf(x.w);
        s[4] = f2bf(y.x); s[5] = f2bf(y.y); s[6] = f2bf(y.z); s[7] = f2bf(y.w);
    }
    *(u16x8*)(Ebf + (size_t)tok * 4096 + r * 128 + d8) = s;
}

// ---------- time features + all adaLN modulation vectors ----------
// MOD layout (f32): [0,1024) sm: b*256+c ; [1024,4096) ada1: (l*4+b)*256+c ; [4096,7168) ada2
__global__ __launch_bounds__(256) void k_prep(
    const float* __restrict__ t,
    const float* __restrict__ smadaW, const float* __restrict__ smadab,
    const float* __restrict__ a1W, const float* __restrict__ a1b,
    const float* __restrict__ a2W, const float* __restrict__ a2b,
    float* __restrict__ MOD)
{
    __shared__ float tf[4][128];
    int tid = threadIdx.x;
    {
        int b = tid >> 6, i = tid & 63;
        float wn = __expf(-(float)i * (9.210340371976184f / 64.0f)); // 10000^(-2i/128)
        float ph = t[b] * wn;
        tf[b][2 * i]     = sinf(ph);
        tf[b][2 * i + 1] = cosf(ph);
    }
    __syncthreads();
    int o = blockIdx.x * 256 + tid;   // 0..7167
    int b, c;
    const float* W; const float* bias; float* out;
    if (o < 1024) {
        b = o >> 8; c = o & 255; W = smadaW; bias = smadab; out = MOD + o;
    } else if (o < 4096) {
        int oo = o - 1024; int lb = oo >> 8; int l = lb >> 2;
        b = lb & 3; c = oo & 255;
        W = a1W + l * 32768; bias = a1b + l * 256; out = MOD + o;
    } else {
        int oo = o - 4096; int lb = oo >> 8; int l = lb >> 2;
        b = lb & 3; c = oo & 255;
        W = a2W + l * 32768; bias = a2b + l * 256; out = MOD + 4096 + oo;
    }
    float s = bias[c];
    const float* tfb = tf[b];
    #pragma unroll 8
    for (int k = 0; k < 128; ++k) s += tfb[k] * W[k * 256 + c];
    *out = s;
}

// ---------- sequence messenger MLP + adaLN -> Vbuf ----------
__global__ __launch_bounds__(256) void k_msgr(
    const float* __restrict__ V, const float* __restrict__ Z,
    const unsigned short* __restrict__ WTG,
    const float* __restrict__ smb1, const float* __restrict__ smb2,
    const float* __restrict__ MOD, float* __restrict__ Vout)
{
    __shared__ __align__(16) unsigned short WT[128 * 136];
    __shared__ __align__(16) float XB[64 * 132];
    const int tid = threadIdx.x;
    const int w = tid >> 6, l = tid & 63, lr = l & 15, lg = l >> 4;
    const int tok0 = blockIdx.x * 64;
    const int batch = tok0 >> 11;
    const int rowA = tok0 + w * 16 + lr;

    f32x4 acc[8] = {};
    for (int kh = 0; kh < 2; ++kh) {
        __syncthreads();
        stage_wt(WT, WTG + kh * 16384, tid, 256);
        __syncthreads();
        const float* A = (kh == 0) ? V : Z;
        #pragma unroll
        for (int ks = 0; ks < 4; ++ks) {
            bf16x8 a = aload_f32(A + rowA * 128 + ks * 32 + lg * 8);
            #pragma unroll
            for (int c = 0; c < 8; ++c)
                acc[c] = mfma16(a, bload(WT, c * 16 + lr, ks * 32 + lg * 8), acc[c]);
        }
    }
    // h1 = gelu(acc + b1) -> XB (transposed through LDS)
    #pragma unroll
    for (int c = 0; c < 8; ++c) {
        int col = c * 16 + lr;
        float b1v = smb1[col];
        #pragma unroll
        for (int j = 0; j < 4; ++j)
            XB[(w * 16 + lg * 4 + j) * 132 + col] = gelu_f(acc[c][j] + b1v);
    }
    __syncthreads();
    stage_wt(WT, WTG + 2 * 16384, tid, 256);
    __syncthreads();
    f32x4 acc2[8] = {};
    #pragma unroll
    for (int ks = 0; ks < 4; ++ks) {
        bf16x8 a = aload_f32(XB + (w * 16 + lr) * 132 + ks * 32 + lg * 8);
        #pragma unroll
        for (int c = 0; c < 8; ++c)
            acc2[c] = mfma16(a, bload(WT, c * 16 + lr, ks * 32 + lg * 8), acc2[c]);
    }
    const float* MODp = MOD + batch * 256;
    #pragma unroll
    for (int j = 0; j < 4; ++j) {
        int row = tok0 + w * 16 + lg * 4 + j;
        float xv[8], s1 = 0.f, s2 = 0.f;
        #pragma unroll
        for (int c = 0; c < 8; ++c) {
            int col = c * 16 + lr;
            float x = acc2[c][j] + smb2[col] + V[row * 128 + col];
            xv[c] = x; s1 += x; s2 += x * x;
        }
        #pragma unroll
        for (int m = 1; m <= 8; m <<= 1) { s1 += __shfl_xor(s1, m); s2 += __shfl_xor(s2, m); }
        float mu = s1 * (1.0f / 128.0f);
        float var = s2 * (1.0f / 128.0f) - mu * mu;
        float rs = rsqrtf(var + 1e-5f);
        #pragma unroll
        for (int c = 0; c < 8; ++c) {
            int col = c * 16 + lr;
            Vout[row * 128 + col] = (xv[c] - mu) * rs * (1.0f + MODp[col]) + MODp[128 + col];
        }
    }
}

// ---------- per-layer: TAB = [ V@W1a + b1 | V@W1c ] ----------
__global__ __launch_bounds__(256) void k_tab(
    const float* __restrict__ Vb, const unsigned short* __restrict__ WTa,
    const unsigned short* __restrict__ WTc, const float* __restrict__ b1,
    float* __restrict__ TAB)
{
    __shared__ __align__(16) unsigned short WT[128 * 136];
    const int tid = threadIdx.x;
    const int w = tid >> 6, l = tid & 63, lr = l & 15, lg = l >> 4;
    const int tok0 = blockIdx.x * 64;
    const int rowA = tok0 + w * 16 + lr;

    stage_wt(WT, WTa, tid, 256);
    __syncthreads();
    f32x4 acc[8] = {};
    #pragma unroll
    for (int ks = 0; ks < 4; ++ks) {
        bf16x8 a = aload_f32(Vb + rowA * 128 + ks * 32 + lg * 8);
        #pragma unroll
        for (int c = 0; c < 8; ++c)
            acc[c] = mfma16(a, bload(WT, c * 16 + lr, ks * 32 + lg * 8), acc[c]);
    }
    #pragma unroll
    for (int c = 0; c < 8; ++c) {
        int col = c * 16 + lr;
        float b1v = b1[col];
        #pragma unroll
        for (int j = 0; j < 4; ++j) {
            int row = tok0 + w * 16 + lg * 4 + j;
            TAB[row * 256 + col] = acc[c][j] + b1v;
        }
    }
    __syncthreads();
    stage_wt(WT, WTc, tid, 256);
    __syncthreads();
    f32x4 acc2[8] = {};
    #pragma unroll
    for (int ks = 0; ks < 4; ++ks) {
        bf16x8 a = aload_f32(Vb + rowA * 128 + ks * 32 + lg * 8);
        #pragma unroll
        for (int c = 0; c < 8; ++c)
            acc2[c] = mfma16(a, bload(WT, c * 16 + lr, ks * 32 + lg * 8), acc2[c]);
    }
    #pragma unroll
    for (int c = 0; c < 8; ++c) {
        int col = c * 16 + lr;
        #pragma unroll
        for (int j = 0; j < 4; ++j) {
            int row = tok0 + w * 16 + lg * 4 + j;
            TAB[row * 256 + 128 + col] = acc2[c][j];
        }
    }
}

// ---------- per-layer edge kernel v2 ----------
// One wave = one token-half (64 cols). No LDS; B frags in VGPRs from L2-hot WTb.
// S[tok] = sum_k gelu(TA + E@W1b + TB[nbr])
template<int EBF>
__global__ __launch_bounds__(256, 3) void k_edge2(
    const float* __restrict__ Ef, const unsigned short* __restrict__ Ebf,
    const int* __restrict__ Kidx, const float* __restrict__ TAB,
    const unsigned short* __restrict__ WTb, float* __restrict__ S)
{
    const int tid = threadIdx.x;
    const int w = tid >> 6, l = tid & 63, lr = l & 15, lg = l >> 4;
    const int colb = (w & 1) * 64;
    const int tokg = blockIdx.x * 2 + (w >> 1);
    const int b = tokg >> 11;

    // B fragments (16 x 16B), identical across blocks -> L1/L2 broadcast
    bf16x8 bf[16];
    #pragma unroll
    for (int nt = 0; nt < 4; ++nt)
        #pragma unroll
        for (int ks = 0; ks < 4; ++ks)
            bf[nt * 4 + ks] = uload(WTb + (colb + nt * 16 + lr) * 128 + ks * 32 + lg * 8);

    // neighbor indices for this lane's output rows
    const int* Kp = Kidx + tokg * 30;
    int nb[8];
    #pragma unroll
    for (int rt = 0; rt < 2; ++rt)
        #pragma unroll
        for (int j = 0; j < 4; ++j) {
            int r = rt * 16 + lg * 4 + j;
            nb[rt * 4 + j] = (r < 30) ? Kp[r] : 0;
        }

    // per-token A addend
    float ta[4];
    #pragma unroll
    for (int nt = 0; nt < 4; ++nt) ta[nt] = TAB[tokg * 256 + colb + nt * 16 + lr];

    // A fragments: 8 x 16B, issued up front
    bf16x8 af[8];
    if (EBF) {
        const unsigned short* ep = Ebf + (size_t)tokg * 4096 + lr * 128 + lg * 8;
        #pragma unroll
        for (int rt = 0; rt < 2; ++rt)
            #pragma unroll
            for (int ks = 0; ks < 4; ++ks)
                af[rt * 4 + ks] = uload(ep + rt * 2048 + ks * 32);
    } else {
        #pragma unroll
        for (int rt = 0; rt < 2; ++rt) {
            int e = rt * 16 + lr; if (e > 29) e = 29;
            const float* ep = Ef + (size_t)tokg * 3840 + e * 128 + lg * 8;
            #pragma unroll
            for (int ks = 0; ks < 4; ++ks) af[rt * 4 + ks] = aload_f32(ep + ks * 32);
        }
    }

    float sacc[4] = {0.f, 0.f, 0.f, 0.f};
    #pragma unroll
    for (int rt = 0; rt < 2; ++rt) {
        // issue TB gathers before the MFMA block so latency hides under MFMA
        float tb[16];
        #pragma unroll
        for (int j = 0; j < 4; ++j) {
            const float* tp = TAB + (size_t)((b << 11) + nb[rt * 4 + j]) * 256 + 128 + colb + lr;
            #pragma unroll
            for (int nt = 0; nt < 4; ++nt) tb[j * 4 + nt] = tp[nt * 16];
        }
        f32x4 acc[4] = {};
        #pragma unroll
        for (int ks = 0; ks < 4; ++ks)
            #pragma unroll
            for (int nt = 0; nt < 4; ++nt)
                acc[nt] = mfma16(af[rt * 4 + ks], bf[nt * 4 + ks], acc[nt]);
        #pragma unroll
        for (int j = 0; j < 4; ++j) {
            int r = rt * 16 + lg * 4 + j;
            if (r < 30) {
                #pragma unroll
                for (int nt = 0; nt < 4; ++nt)
                    sacc[nt] += gelu_f(acc[nt][j] + ta[nt] + tb[j * 4 + nt]);
            }
        }
    }
    #pragma unroll
    for (int nt = 0; nt < 4; ++nt) {
        sacc[nt] += __shfl_xor(sacc[nt], 16);
        sacc[nt] += __shfl_xor(sacc[nt], 32);
    }
    if (l < 16) {
        #pragma unroll
        for (int nt = 0; nt < 4; ++nt)
            S[tokg * 128 + colb + nt * 16 + l] = sacc[nt];
    }
}

// ---------- per-layer token kernel: dV/W2, adaLN, FFN, adaLN (+ optional proj) ----------
__global__ __launch_bounds__(256) void k_token(
    const float* __restrict__ Sb, const float* __restrict__ Vb,
    const unsigned short* __restrict__ WTW2, const float* __restrict__ b2,
    const unsigned short* __restrict__ WTF1, const float* __restrict__ fb1,
    const unsigned short* __restrict__ WTF2, const float* __restrict__ fb2,
    const unsigned short* __restrict__ WTP,
    const float* __restrict__ MOD1, const float* __restrict__ MOD2,
    float* __restrict__ Vout, int final_)
{
    __shared__ __align__(16) unsigned short WT[128 * 136];
    __shared__ __align__(16) float XB[64 * 132];
    const int tid = threadIdx.x;
    const int w = tid >> 6, l = tid & 63, lr = l & 15, lg = l >> 4;
    const int tok0 = blockIdx.x * 64;
    const int batch = tok0 >> 11;
    const int rloc = w * 16 + lr;

    stage_wt(WT, WTW2, tid, 256);
    __syncthreads();
    f32x4 acc[8] = {};
    #pragma unroll
    for (int ks = 0; ks < 4; ++ks) {
        bf16x8 a = aload_f32(Sb + (tok0 + rloc) * 128 + ks * 32 + lg * 8);
        #pragma unroll
        for (int c = 0; c < 8; ++c)
            acc[c] = mfma16(a, bload(WT, c * 16 + lr, ks * 32 + lg * 8), acc[c]);
    }
    const float* M1 = MOD1 + batch * 256;
    const float* M2 = MOD2 + batch * 256;
    float vp[8][4];
    #pragma unroll
    for (int j = 0; j < 4; ++j) {
        int row = tok0 + w * 16 + lg * 4 + j;
        float xv[8], s1 = 0.f, s2 = 0.f;
        #pragma unroll
        for (int c = 0; c < 8; ++c) {
            int col = c * 16 + lr;
            float x = acc[c][j] * (1.0f / 30.0f) + b2[col] + Vb[row * 128 + col];
            xv[c] = x; s1 += x; s2 += x * x;
        }
        #pragma unroll
        for (int m = 1; m <= 8; m <<= 1) { s1 += __shfl_xor(s1, m); s2 += __shfl_xor(s2, m); }
        float mu = s1 * (1.0f / 128.0f);
        float var = s2 * (1.0f / 128.0f) - mu * mu;
        float rs = rsqrtf(var + 1e-5f);
        #pragma unroll
        for (int c = 0; c < 8; ++c) {
            int col = c * 16 + lr;
            vp[c][j] = (xv[c] - mu) * rs * (1.0f + M1[col]) + M1[128 + col];
        }
    }
    __syncthreads();
    #pragma unroll
    for (int c = 0; c < 8; ++c)
        #pragma unroll
        for (int j = 0; j < 4; ++j)
            XB[(w * 16 + lg * 4 + j) * 132 + c * 16 + lr] = vp[c][j];
    stage_wt(WT, WTF1, tid, 256);
    __syncthreads();
    f32x4 accB[8] = {};
    #pragma unroll
    for (int ks = 0; ks < 4; ++ks) {
        bf16x8 a = aload_f32(XB + rloc * 132 + ks * 32 + lg * 8);
        #pragma unroll
        for (int c = 0; c < 8; ++c)
            accB[c] = mfma16(a, bload(WT, c * 16 + lr, ks * 32 + lg * 8), accB[c]);
    }
    __syncthreads();
    #pragma unroll
    for (int c = 0; c < 8; ++c) {
        int col = c * 16 + lr;
        float bv = fb1[col];
        #pragma unroll
        for (int j = 0; j < 4; ++j)
            XB[(w * 16 + lg * 4 + j) * 132 + col] = gelu_f(accB[c][j] + bv);
    }
    stage_wt(WT, WTF2, tid, 256);
    __syncthreads();
    f32x4 accC[8] = {};
    #pragma unroll
    for (int ks = 0; ks < 4; ++ks) {
        bf16x8 a = aload_f32(XB + rloc * 132 + ks * 32 + lg * 8);
        #pragma unroll
        for (int c = 0; c < 8; ++c)
            accC[c] = mfma16(a, bload(WT, c * 16 + lr, ks * 32 + lg * 8), accC[c]);
    }
    float v2[8][4];
    #pragma unroll
    for (int j = 0; j < 4; ++j) {
        float xv[8], s1 = 0.f, s2 = 0.f;
        #pragma unroll
        for (int c = 0; c < 8; ++c) {
            int col = c * 16 + lr;
            float x = accC[c][j] + fb2[col] + vp[c][j];
            xv[c] = x; s1 += x; s2 += x * x;
        }
        #pragma unroll
        for (int m = 1; m <= 8; m <<= 1) { s1 += __shfl_xor(s1, m); s2 += __shfl_xor(s2, m); }
        float mu = s1 * (1.0f / 128.0f);
        float var = s2 * (1.0f / 128.0f) - mu * mu;
        float rs = rsqrtf(var + 1e-5f);
        #pragma unroll
        for (int c = 0; c < 8; ++c) {
            int col = c * 16 + lr;
            v2[c][j] = (xv[c] - mu) * rs * (1.0f + M2[col]) + M2[128 + col];
        }
    }
    if (!final_) {
        #pragma unroll
        for (int c = 0; c < 8; ++c)
            #pragma unroll
            for (int j = 0; j < 4; ++j)
                Vout[(tok0 + w * 16 + lg * 4 + j) * 128 + c * 16 + lr] = v2[c][j];
    } else {
        __syncthreads();
        #pragma unroll
        for (int c = 0; c < 8; ++c)
            #pragma unroll
            for (int j = 0; j < 4; ++j)
                XB[(w * 16 + lg * 4 + j) * 132 + c * 16 + lr] = v2[c][j];
        stage_wt(WT, WTP, tid, 256);
        __syncthreads();
        f32x4 accD[8] = {};
        #pragma unroll
        for (int ks = 0; ks < 4; ++ks) {
            bf16x8 a = aload_f32(XB + rloc * 132 + ks * 32 + lg * 8);
            #pragma unroll
            for (int c = 0; c < 8; ++c)
                accD[c] = mfma16(a, bload(WT, c * 16 + lr, ks * 32 + lg * 8), accD[c]);
        }
        #pragma unroll
        for (int c = 0; c < 8; ++c)
            #pragma unroll
            for (int j = 0; j < 4; ++j)
                Vout[(tok0 + w * 16 + lg * 4 + j) * 128 + c * 16 + lr] = accD[c][j];
    }
}

// ---------- host ----------

extern "C" void kernel_launch(void* const* d_in, const int* in_sizes, int n_in,
                              void* d_out, int out_size, void* d_ws, size_t ws_size,
                              hipStream_t stream)
{
    const float* V     = (const float*)d_in[0];
    const float* E     = (const float*)d_in[1];
    const int*   K     = (const int*)d_in[2];
    const float* Z     = (const float*)d_in[3];
    const float* t     = (const float*)d_in[4];
    // d_in[5] = edge_mask (all true in this problem; msg mask is identity)
    const float* smW1   = (const float*)d_in[6];
    const float* smb1   = (const float*)d_in[7];
    const float* smW2   = (const float*)d_in[8];
    const float* smb2   = (const float*)d_in[9];
    const float* smadaW = (const float*)d_in[10];
    const float* smadab = (const float*)d_in[11];
    const float* msgW1  = (const float*)d_in[12];
    const float* msgb1  = (const float*)d_in[13];
    const float* msgW2  = (const float*)d_in[14];
    const float* msgb2  = (const float*)d_in[15];
    const float* a1W    = (const float*)d_in[16];
    const float* a1b    = (const float*)d_in[17];
    const float* fW1    = (const float*)d_in[18];
    const float* fb1    = (const float*)d_in[19];
    const float* fW2    = (const float*)d_in[20];
    const float* fb2    = (const float*)d_in[21];
    const float* a2W    = (const float*)d_in[22];
    const float* a2b    = (const float*)d_in[23];
    const float* projW  = (const float*)d_in[24];

    float* Vbuf = (float*)d_ws;                  // 8192*128 f32
    float* TAB  = Vbuf + 8192 * 128;             // 8192*256 f32
    float* Sb   = TAB + 8192 * 256;              // 8192*128 f32
    float* MOD  = Sb + 8192 * 128;               // 7168 f32
    unsigned short* WTG = (unsigned short*)(MOD + 7168);  // 22*16384 u16
    unsigned short* Ebf = WTG + 22 * 16384;      // 8192*4096 u16 (64 MB, optional)

    size_t need = (size_t)(8192 * 128 + 8192 * 256 + 8192 * 128 + 7168) * 4
                + (size_t)22 * 16384 * 2 + (size_t)8192 * 4096 * 2;
    const int use_bf = (ws_size >= need) ? 1 : 0;

    k_wconv<<<dim3(176), dim3(256), 0, stream>>>(smW1, smW2, projW, msgW1, msgW2, fW1, fW2, WTG);
    k_prep<<<dim3(28), dim3(256), 0, stream>>>(t, smadaW, smadab, a1W, a1b, a2W, a2b, MOD);
    if (use_bf)
        k_econv<<<dim3(16384), dim3(256), 0, stream>>>(E, Ebf);
    k_msgr<<<dim3(128), dim3(256), 0, stream>>>(V, Z, WTG, smb1, smb2, MOD, Vbuf);

    for (int l = 0; l < 3; ++l) {
        const unsigned short* Wl = WTG + (4 + l * 6) * 16384;
        k_tab<<<dim3(128), dim3(256), 0, stream>>>(Vbuf, Wl, Wl + 2 * 16384, msgb1 + l * 128, TAB);
        if (use_bf)
            k_edge2<1><<<dim3(4096), dim3(256), 0, stream>>>(E, Ebf, K, TAB, Wl + 16384, Sb);
        else
            k_edge2<0><<<dim3(4096), dim3(256), 0, stream>>>(E, Ebf, K, TAB, Wl + 16384, Sb);
        int fin = (l == 2);
        k_token<<<dim3(128), dim3(256), 0, stream>>>(
            Sb, Vbuf, Wl + 3 * 16384, msgb2 + l * 128,
            Wl + 4 * 16384, fb1 + l * 128, Wl + 5 * 16384, fb2 + l * 128,
            WTG + 3 * 16384,
            MOD + 1024 + l * 1024, MOD + 4096 + l * 1024,
            fin ? (float*)d_out : Vbuf, fin);
    }
}

// Round 3
// 270.732 us; speedup vs baseline: 1.0554x; 1.0554x over previous
//
#include <hip/hip_runtime.h>
#include <hip/hip_bf16.h>

#define DEV static __device__ __forceinline__

typedef __bf16 bf16x8 __attribute__((ext_vector_type(8)));
typedef unsigned short u16x8 __attribute__((ext_vector_type(8)));
typedef unsigned short u16x4 __attribute__((ext_vector_type(4)));
typedef float f32x4 __attribute__((ext_vector_type(4)));

// ---------- helpers ----------

DEV unsigned short f2bf(float f) {
    unsigned u = __builtin_bit_cast(unsigned, f);
    u += 0x7FFFu + ((u >> 16) & 1u);          // RNE (finite inputs only)
    return (unsigned short)(u >> 16);
}

DEV float bf2f(unsigned short v) {
    return __builtin_bit_cast(float, (unsigned)v << 16);
}

DEV float gelu_f(float x) {
    // tanh-approx gelu == x * sigmoid(1.5957691*(x + 0.044715 x^3)) (matches jax.nn.gelu)
    float u = x * (1.0f + 0.044715f * x * x);
    return x / (1.0f + __expf(-1.5957691216057308f * u));
}

DEV f32x4 mfma16(bf16x8 a, bf16x8 b, f32x4 c) {
    return __builtin_amdgcn_mfma_f32_16x16x32_bf16(a, b, c, 0, 0, 0);
}

// load 8 consecutive f32 (16B-aligned) -> bf16x8
DEV bf16x8 aload_f32(const float* p) {
    float4 x = *(const float4*)p;
    float4 y = *(const float4*)(p + 4);
    u16x8 s;
    s[0] = f2bf(x.x); s[1] = f2bf(x.y); s[2] = f2bf(x.z); s[3] = f2bf(x.w);
    s[4] = f2bf(y.x); s[5] = f2bf(y.y); s[6] = f2bf(y.z); s[7] = f2bf(y.w);
    return __builtin_bit_cast(bf16x8, s);
}

DEV bf16x8 uload(const unsigned short* p) {
    return __builtin_bit_cast(bf16x8, *(const u16x8*)(p));
}

// B-fragment read from LDS WT[n][k] (stride 136 u16), col = n, koff = k start (mult of 8)
DEV bf16x8 bload(const unsigned short* WT, int col, int koff) {
    return __builtin_bit_cast(bf16x8, *(const u16x8*)(WT + col * 136 + koff));
}

// copy pre-transposed bf16 weight [128n][128k] from global into LDS WT[n*136+k]
DEV void stage_wt(unsigned short* WT, const unsigned short* src, int tid, int nthr) {
    for (int i = tid; i < 2048; i += nthr) {
        int n = i >> 4, k0 = (i & 15) << 3;
        *(u16x8*)(WT + n * 136 + k0) = *(const u16x8*)(src + n * 128 + k0);
    }
}

// ---------- weight pre-transpose: f32 [128k][128n] -> bf16 [128n][128k] ----------
// 22 matrices of 128x128: 0 smW1(V-half) 1 smW1(Z-half) 2 smW2 3 proj,
// then per layer l: 4+6l+{0:W1a,1:W1b,2:W1c,3:msgW2,4:ffnW1,5:ffnW2}
__global__ __launch_bounds__(256) void k_wconv(
    const float* __restrict__ smW1, const float* __restrict__ smW2,
    const float* __restrict__ projW, const float* __restrict__ msgW1,
    const float* __restrict__ msgW2, const float* __restrict__ ffnW1,
    const float* __restrict__ ffnW2, unsigned short* __restrict__ WTG)
{
    int m = blockIdx.x >> 3;
    int chunk = blockIdx.x & 7;
    const float* src;
    if (m == 0) src = smW1;
    else if (m == 1) src = smW1 + 16384;
    else if (m == 2) src = smW2;
    else if (m == 3) src = projW;
    else {
        int mm = m - 4; int l = mm / 6; int j = mm % 6;
        if (j < 3)      src = msgW1 + l * 49152 + j * 16384;
        else if (j == 3) src = msgW2 + l * 16384;
        else if (j == 4) src = ffnW1 + l * 16384;
        else             src = ffnW2 + l * 16384;
    }
    unsigned short* dst = WTG + m * 16384;
    int s0 = chunk * 2048 + threadIdx.x * 8;   // flat src index, k = s0>>7, n = s0&127
    int k = s0 >> 7, n = s0 & 127;
    float4 x = *(const float4*)(src + s0);
    float4 y = *(const float4*)(src + s0 + 4);
    dst[(n + 0) * 128 + k] = f2bf(x.x);
    dst[(n + 1) * 128 + k] = f2bf(x.y);
    dst[(n + 2) * 128 + k] = f2bf(x.z);
    dst[(n + 3) * 128 + k] = f2bf(x.w);
    dst[(n + 4) * 128 + k] = f2bf(y.x);
    dst[(n + 5) * 128 + k] = f2bf(y.y);
    dst[(n + 6) * 128 + k] = f2bf(y.z);
    dst[(n + 7) * 128 + k] = f2bf(y.w);
}

// ---------- time features + all adaLN modulation vectors ----------
// MOD layout (f32): [0,1024) sm: b*256+c ; [1024,4096) ada1: (l*4+b)*256+c ; [4096,7168) ada2
__global__ __launch_bounds__(256) void k_prep(
    const float* __restrict__ t,
    const float* __restrict__ smadaW, const float* __restrict__ smadab,
    const float* __restrict__ a1W, const float* __restrict__ a1b,
    const float* __restrict__ a2W, const float* __restrict__ a2b,
    float* __restrict__ MOD)
{
    __shared__ float tf[4][128];
    int tid = threadIdx.x;
    {
        int b = tid >> 6, i = tid & 63;
        float wn = __expf(-(float)i * (9.210340371976184f / 64.0f)); // 10000^(-2i/128)
        float ph = t[b] * wn;
        tf[b][2 * i]     = sinf(ph);
        tf[b][2 * i + 1] = cosf(ph);
    }
    __syncthreads();
    int o = blockIdx.x * 256 + tid;   // 0..7167
    int b, c;
    const float* W; const float* bias; float* out;
    if (o < 1024) {
        b = o >> 8; c = o & 255; W = smadaW; bias = smadab; out = MOD + o;
    } else if (o < 4096) {
        int oo = o - 1024; int lb = oo >> 8; int l = lb >> 2;
        b = lb & 3; c = oo & 255;
        W = a1W + l * 32768; bias = a1b + l * 256; out = MOD + o;
    } else {
        int oo = o - 4096; int lb = oo >> 8; int l = lb >> 2;
        b = lb & 3; c = oo & 255;
        W = a2W + l * 32768; bias = a2b + l * 256; out = MOD + 4096 + oo;
    }
    float s = bias[c];
    const float* tfb = tf[b];
    #pragma unroll 8
    for (int k = 0; k < 128; ++k) s += tfb[k] * W[k * 256 + c];
    *out = s;
}

// ---------- sequence messenger MLP + adaLN -> Vbuf ----------
__global__ __launch_bounds__(256) void k_msgr(
    const float* __restrict__ V, const float* __restrict__ Z,
    const unsigned short* __restrict__ WTG,
    const float* __restrict__ smb1, const float* __restrict__ smb2,
    const float* __restrict__ MOD, float* __restrict__ Vout)
{
    __shared__ __align__(16) unsigned short WT[128 * 136];
    __shared__ __align__(16) float XB[64 * 132];
    const int tid = threadIdx.x;
    const int w = tid >> 6, l = tid & 63, lr = l & 15, lg = l >> 4;
    const int tok0 = blockIdx.x * 64;
    const int batch = tok0 >> 11;
    const int rowA = tok0 + w * 16 + lr;

    f32x4 acc[8] = {};
    for (int kh = 0; kh < 2; ++kh) {
        __syncthreads();
        stage_wt(WT, WTG + kh * 16384, tid, 256);
        __syncthreads();
        const float* A = (kh == 0) ? V : Z;
        #pragma unroll
        for (int ks = 0; ks < 4; ++ks) {
            bf16x8 a = aload_f32(A + rowA * 128 + ks * 32 + lg * 8);
            #pragma unroll
            for (int c = 0; c < 8; ++c)
                acc[c] = mfma16(a, bload(WT, c * 16 + lr, ks * 32 + lg * 8), acc[c]);
        }
    }
    // h1 = gelu(acc + b1) -> XB (transposed through LDS)
    #pragma unroll
    for (int c = 0; c < 8; ++c) {
        int col = c * 16 + lr;
        float b1v = smb1[col];
        #pragma unroll
        for (int j = 0; j < 4; ++j)
            XB[(w * 16 + lg * 4 + j) * 132 + col] = gelu_f(acc[c][j] + b1v);
    }
    __syncthreads();
    stage_wt(WT, WTG + 2 * 16384, tid, 256);
    __syncthreads();
    f32x4 acc2[8] = {};
    #pragma unroll
    for (int ks = 0; ks < 4; ++ks) {
        bf16x8 a = aload_f32(XB + (w * 16 + lr) * 132 + ks * 32 + lg * 8);
        #pragma unroll
        for (int c = 0; c < 8; ++c)
            acc2[c] = mfma16(a, bload(WT, c * 16 + lr, ks * 32 + lg * 8), acc2[c]);
    }
    const float* MODp = MOD + batch * 256;
    #pragma unroll
    for (int j = 0; j < 4; ++j) {
        int row = tok0 + w * 16 + lg * 4 + j;
        float xv[8], s1 = 0.f, s2 = 0.f;
        #pragma unroll
        for (int c = 0; c < 8; ++c) {
            int col = c * 16 + lr;
            float x = acc2[c][j] + smb2[col] + V[row * 128 + col];
            xv[c] = x; s1 += x; s2 += x * x;
        }
        #pragma unroll
        for (int m = 1; m <= 8; m <<= 1) { s1 += __shfl_xor(s1, m); s2 += __shfl_xor(s2, m); }
        float mu = s1 * (1.0f / 128.0f);
        float var = s2 * (1.0f / 128.0f) - mu * mu;
        float rs = rsqrtf(var + 1e-5f);
        #pragma unroll
        for (int c = 0; c < 8; ++c) {
            int col = c * 16 + lr;
            Vout[row * 128 + col] = (xv[c] - mu) * rs * (1.0f + MODp[col]) + MODp[128 + col];
        }
    }
}

// ---------- per-layer: TA = V@W1a + b1 (f32), TB = V@W1c (bf16) ----------
__global__ __launch_bounds__(256) void k_tab(
    const float* __restrict__ Vb, const unsigned short* __restrict__ WTa,
    const unsigned short* __restrict__ WTc, const float* __restrict__ b1,
    float* __restrict__ TAf, unsigned short* __restrict__ TBb)
{
    __shared__ __align__(16) unsigned short WT[128 * 136];
    const int tid = threadIdx.x;
    const int w = tid >> 6, l = tid & 63, lr = l & 15, lg = l >> 4;
    const int tok0 = blockIdx.x * 64;
    const int rowA = tok0 + w * 16 + lr;

    stage_wt(WT, WTa, tid, 256);
    __syncthreads();
    f32x4 acc[8] = {};
    #pragma unroll
    for (int ks = 0; ks < 4; ++ks) {
        bf16x8 a = aload_f32(Vb + rowA * 128 + ks * 32 + lg * 8);
        #pragma unroll
        for (int c = 0; c < 8; ++c)
            acc[c] = mfma16(a, bload(WT, c * 16 + lr, ks * 32 + lg * 8), acc[c]);
    }
    #pragma unroll
    for (int c = 0; c < 8; ++c) {
        int col = c * 16 + lr;
        float b1v = b1[col];
        #pragma unroll
        for (int j = 0; j < 4; ++j) {
            int row = tok0 + w * 16 + lg * 4 + j;
            TAf[row * 128 + col] = acc[c][j] + b1v;
        }
    }
    __syncthreads();
    stage_wt(WT, WTc, tid, 256);
    __syncthreads();
    f32x4 acc2[8] = {};
    #pragma unroll
    for (int ks = 0; ks < 4; ++ks) {
        bf16x8 a = aload_f32(Vb + rowA * 128 + ks * 32 + lg * 8);
        #pragma unroll
        for (int c = 0; c < 8; ++c)
            acc2[c] = mfma16(a, bload(WT, c * 16 + lr, ks * 32 + lg * 8), acc2[c]);
    }
    #pragma unroll
    for (int c = 0; c < 8; ++c) {
        int col = c * 16 + lr;
        #pragma unroll
        for (int j = 0; j < 4; ++j) {
            int row = tok0 + w * 16 + lg * 4 + j;
            TBb[row * 128 + col] = f2bf(acc2[c][j]);
        }
    }
}

// ---------- per-layer edge kernel v3: coalesced LDS staging ----------
// Block: 256 thr / 4 waves / 2 tokens. Wave w: token (w>>1), col-half (w&1).
// S[tok] = sum_k gelu(TA + E@W1b + TB[nbr]); rows r>=30 masked.
// LDS layout: row stride 256 B, 16B-block swizzle: byte ^= (row&7)<<4.
__global__ __launch_bounds__(256, 3) void k_edge3(
    const float* __restrict__ E,            // f32 [8192][30][128]
    const int* __restrict__ Kidx,           // [8192][30]
    const float* __restrict__ TAf,          // f32 [8192][128]
    const unsigned short* __restrict__ TBb, // bf16 [8192][128]
    const unsigned short* __restrict__ WTb, // bf16 [128n][128k]
    float* __restrict__ S)                  // f32 [8192][128]
{
    __shared__ __align__(16) unsigned short EL[2 * 32 * 128];
    __shared__ __align__(16) unsigned short TBL[2 * 32 * 128];
    const int tid = threadIdx.x;
    const int w = tid >> 6, l = tid & 63, lr = l & 15, lg = l >> 4;
    const int tokbase = blockIdx.x * 2;
    const int bbase = (tokbase >> 11) << 11;
    const int nh = w & 1;
    const int tl_w = w >> 1;
    const int tok_w = tokbase + tl_w;

    // B fragments: 16 x 16B scattered but L1/L2-hot (same addrs all blocks); issue first
    bf16x8 bf[16];
    #pragma unroll
    for (int n = 0; n < 4; ++n)
        #pragma unroll
        for (int ks = 0; ks < 4; ++ks)
            bf[n * 4 + ks] = uload(WTb + (nh * 64 + n * 16 + lr) * 128 + ks * 32 + lg * 8);

    // per-token A addend (per-col), issue early
    float ta[4];
    #pragma unroll
    for (int n = 0; n < 4; ++n) ta[n] = TAf[tok_w * 128 + nh * 64 + n * 16 + lr];

    // stage E (f32 -> bf16, coalesced, swizzled): 2 tok x 30 rows x 32 float4-chunks
    #pragma unroll
    for (int it = 0; it < 8; ++it) {
        int s = it * 256 + tid;
        if (s < 1920) {
            int tl = (s >= 960) ? 1 : 0;
            int rem = s - tl * 960;
            int r = rem >> 5;
            int q = rem & 31;
            float4 x = *(const float4*)(E + ((size_t)(tokbase + tl) * 30 + r) * 128 + q * 4);
            u16x4 pk;
            pk[0] = f2bf(x.x); pk[1] = f2bf(x.y); pk[2] = f2bf(x.z); pk[3] = f2bf(x.w);
            *(u16x4*)((char*)EL + tl * 8192 + r * 256 + ((q * 8) ^ ((r & 7) << 4))) = pk;
        }
    }
    // stage TB neighbor rows (bf16, 256B coalesced granules, swizzled): 2 tok x 32 rows x 16 segs
    #pragma unroll
    for (int it = 0; it < 4; ++it) {
        int s = it * 256 + tid;
        int tl = s >> 9;
        int r = (s >> 4) & 31;
        int q = s & 15;
        int nbr = (r < 30) ? Kidx[(tokbase + tl) * 30 + r] : 0;
        u16x8 v = *(const u16x8*)(TBb + (size_t)(bbase + nbr) * 128 + q * 8);
        *(u16x8*)((char*)TBL + tl * 8192 + r * 256 + ((q * 16) ^ ((r & 7) << 4))) = v;
    }
    __syncthreads();

    // MFMA: per wave, M = 32 rows (2 tiles), N = 64 cols (4 tiles), K = 128
    const char* ebase = (const char*)EL + tl_w * 8192;
    f32x4 acc[2][4] = {};
    #pragma unroll
    for (int m = 0; m < 2; ++m) {
        bf16x8 ar[4];
        #pragma unroll
        for (int ks = 0; ks < 4; ++ks)
            ar[ks] = *(const bf16x8*)(ebase + (m * 16 + lr) * 256 +
                                      (((ks * 32 + lg * 8) * 2) ^ ((lr & 7) << 4)));
        #pragma unroll
        for (int ks = 0; ks < 4; ++ks)
            #pragma unroll
            for (int n = 0; n < 4; ++n)
                acc[m][n] = mfma16(ar[ks], bf[n * 4 + ks], acc[m][n]);
    }

    // epilogue: add TA + TB[nbr], gelu, reduce over rows
    const char* tbase = (const char*)TBL + tl_w * 8192;
    float sacc[4] = {0.f, 0.f, 0.f, 0.f};
    #pragma unroll
    for (int m = 0; m < 2; ++m)
        #pragma unroll
        for (int n = 0; n < 4; ++n) {
            int c2 = (nh * 64 + n * 16 + lr) * 2;
            #pragma unroll
            for (int j = 0; j < 4; ++j) {
                int r = m * 16 + lg * 4 + j;
                if (r < 30) {
                    unsigned short uv = *(const unsigned short*)(tbase + r * 256 + (c2 ^ ((r & 7) << 4)));
                    sacc[n] += gelu_f(acc[m][n][j] + ta[n] + bf2f(uv));
                }
            }
        }
    #pragma unroll
    for (int n = 0; n < 4; ++n) {
        sacc[n] += __shfl_xor(sacc[n], 16);
        sacc[n] += __shfl_xor(sacc[n], 32);
    }
    if (l < 16) {
        #pragma unroll
        for (int n = 0; n < 4; ++n)
            S[tok_w * 128 + nh * 64 + n * 16 + l] = sacc[n];
    }
}

// ---------- per-layer token kernel: dV/W2, adaLN, FFN, adaLN (+ optional proj) ----------
__global__ __launch_bounds__(256) void k_token(
    const float* __restrict__ Sb, const float* __restrict__ Vb,
    const unsigned short* __restrict__ WTW2, const float* __restrict__ b2,
    const unsigned short* __restrict__ WTF1, const float* __restrict__ fb1,
    const unsigned short* __restrict__ WTF2, const float* __restrict__ fb2,
    const unsigned short* __restrict__ WTP,
    const float* __restrict__ MOD1, const float* __restrict__ MOD2,
    float* __restrict__ Vout, int final_)
{
    __shared__ __align__(16) unsigned short WT[128 * 136];
    __shared__ __align__(16) float XB[64 * 132];
    const int tid = threadIdx.x;
    const int w = tid >> 6, l = tid & 63, lr = l & 15, lg = l >> 4;
    const int tok0 = blockIdx.x * 64;
    const int batch = tok0 >> 11;
    const int rloc = w * 16 + lr;

    stage_wt(WT, WTW2, tid, 256);
    __syncthreads();
    f32x4 acc[8] = {};
    #pragma unroll
    for (int ks = 0; ks < 4; ++ks) {
        bf16x8 a = aload_f32(Sb + (tok0 + rloc) * 128 + ks * 32 + lg * 8);
        #pragma unroll
        for (int c = 0; c < 8; ++c)
            acc[c] = mfma16(a, bload(WT, c * 16 + lr, ks * 32 + lg * 8), acc[c]);
    }
    const float* M1 = MOD1 + batch * 256;
    const float* M2 = MOD2 + batch * 256;
    float vp[8][4];
    #pragma unroll
    for (int j = 0; j < 4; ++j) {
        int row = tok0 + w * 16 + lg * 4 + j;
        float xv[8], s1 = 0.f, s2 = 0.f;
        #pragma unroll
        for (int c = 0; c < 8; ++c) {
            int col = c * 16 + lr;
            float x = acc[c][j] * (1.0f / 30.0f) + b2[col] + Vb[row * 128 + col];
            xv[c] = x; s1 += x; s2 += x * x;
        }
        #pragma unroll
        for (int m = 1; m <= 8; m <<= 1) { s1 += __shfl_xor(s1, m); s2 += __shfl_xor(s2, m); }
        float mu = s1 * (1.0f / 128.0f);
        float var = s2 * (1.0f / 128.0f) - mu * mu;
        float rs = rsqrtf(var + 1e-5f);
        #pragma unroll
        for (int c = 0; c < 8; ++c) {
            int col = c * 16 + lr;
            vp[c][j] = (xv[c] - mu) * rs * (1.0f + M1[col]) + M1[128 + col];
        }
    }
    __syncthreads();
    #pragma unroll
    for (int c = 0; c < 8; ++c)
        #pragma unroll
        for (int j = 0; j < 4; ++j)
            XB[(w * 16 + lg * 4 + j) * 132 + c * 16 + lr] = vp[c][j];
    stage_wt(WT, WTF1, tid, 256);
    __syncthreads();
    f32x4 accB[8] = {};
    #pragma unroll
    for (int ks = 0; ks < 4; ++ks) {
        bf16x8 a = aload_f32(XB + rloc * 132 + ks * 32 + lg * 8);
        #pragma unroll
        for (int c = 0; c < 8; ++c)
            accB[c] = mfma16(a, bload(WT, c * 16 + lr, ks * 32 + lg * 8), accB[c]);
    }
    __syncthreads();
    #pragma unroll
    for (int c = 0; c < 8; ++c) {
        int col = c * 16 + lr;
        float bv = fb1[col];
        #pragma unroll
        for (int j = 0; j < 4; ++j)
            XB[(w * 16 + lg * 4 + j) * 132 + col] = gelu_f(accB[c][j] + bv);
    }
    stage_wt(WT, WTF2, tid, 256);
    __syncthreads();
    f32x4 accC[8] = {};
    #pragma unroll
    for (int ks = 0; ks < 4; ++ks) {
        bf16x8 a = aload_f32(XB + rloc * 132 + ks * 32 + lg * 8);
        #pragma unroll
        for (int c = 0; c < 8; ++c)
            accC[c] = mfma16(a, bload(WT, c * 16 + lr, ks * 32 + lg * 8), accC[c]);
    }
    float v2[8][4];
    #pragma unroll
    for (int j = 0; j < 4; ++j) {
        float xv[8], s1 = 0.f, s2 = 0.f;
        #pragma unroll
        for (int c = 0; c < 8; ++c) {
            int col = c * 16 + lr;
            float x = accC[c][j] + fb2[col] + vp[c][j];
            xv[c] = x; s1 += x; s2 += x * x;
        }
        #pragma unroll
        for (int m = 1; m <= 8; m <<= 1) { s1 += __shfl_xor(s1, m); s2 += __shfl_xor(s2, m); }
        float mu = s1 * (1.0f / 128.0f);
        float var = s2 * (1.0f / 128.0f) - mu * mu;
        float rs = rsqrtf(var + 1e-5f);
        #pragma unroll
        for (int c = 0; c < 8; ++c) {
            int col = c * 16 + lr;
            v2[c][j] = (xv[c] - mu) * rs * (1.0f + M2[col]) + M2[128 + col];
        }
    }
    if (!final_) {
        #pragma unroll
        for (int c = 0; c < 8; ++c)
            #pragma unroll
            for (int j = 0; j < 4; ++j)
                Vout[(tok0 + w * 16 + lg * 4 + j) * 128 + c * 16 + lr] = v2[c][j];
    } else {
        __syncthreads();
        #pragma unroll
        for (int c = 0; c < 8; ++c)
            #pragma unroll
            for (int j = 0; j < 4; ++j)
                XB[(w * 16 + lg * 4 + j) * 132 + c * 16 + lr] = v2[c][j];
        stage_wt(WT, WTP, tid, 256);
        __syncthreads();
        f32x4 accD[8] = {};
        #pragma unroll
        for (int ks = 0; ks < 4; ++ks) {
            bf16x8 a = aload_f32(XB + rloc * 132 + ks * 32 + lg * 8);
            #pragma unroll
            for (int c = 0; c < 8; ++c)
                accD[c] = mfma16(a, bload(WT, c * 16 + lr, ks * 32 + lg * 8), accD[c]);
        }
        #pragma unroll
        for (int c = 0; c < 8; ++c)
            #pragma unroll
            for (int j = 0; j < 4; ++j)
                Vout[(tok0 + w * 16 + lg * 4 + j) * 128 + c * 16 + lr] = accD[c][j];
    }
}

// ---------- host ----------

extern "C" void kernel_launch(void* const* d_in, const int* in_sizes, int n_in,
                              void* d_out, int out_size, void* d_ws, size_t ws_size,
                              hipStream_t stream)
{
    const float* V     = (const float*)d_in[0];
    const float* E     = (const float*)d_in[1];
    const int*   K     = (const int*)d_in[2];
    const float* Z     = (const float*)d_in[3];
    const float* t     = (const float*)d_in[4];
    // d_in[5] = edge_mask (all true in this problem; msg mask is identity)
    const float* smW1   = (const float*)d_in[6];
    const float* smb1   = (const float*)d_in[7];
    const float* smW2   = (const float*)d_in[8];
    const float* smb2   = (const float*)d_in[9];
    const float* smadaW = (const float*)d_in[10];
    const float* smadab = (const float*)d_in[11];
    const float* msgW1  = (const float*)d_in[12];
    const float* msgb1  = (const float*)d_in[13];
    const float* msgW2  = (const float*)d_in[14];
    const float* msgb2  = (const float*)d_in[15];
    const float* a1W    = (const float*)d_in[16];
    const float* a1b    = (const float*)d_in[17];
    const float* fW1    = (const float*)d_in[18];
    const float* fb1    = (const float*)d_in[19];
    const float* fW2    = (const float*)d_in[20];
    const float* fb2    = (const float*)d_in[21];
    const float* a2W    = (const float*)d_in[22];
    const float* a2b    = (const float*)d_in[23];
    const float* projW  = (const float*)d_in[24];

    float* Vbuf = (float*)d_ws;                  // 8192*128 f32
    float* TAf  = Vbuf + 8192 * 128;             // 8192*128 f32
    float* Sb   = TAf + 8192 * 128;              // 8192*128 f32
    float* MOD  = Sb + 8192 * 128;               // 7168 f32
    unsigned short* TBb = (unsigned short*)(MOD + 7168);   // 8192*128 u16
    unsigned short* WTG = TBb + 8192 * 128;                // 22*16384 u16

    k_wconv<<<dim3(176), dim3(256), 0, stream>>>(smW1, smW2, projW, msgW1, msgW2, fW1, fW2, WTG);
    k_prep<<<dim3(28), dim3(256), 0, stream>>>(t, smadaW, smadab, a1W, a1b, a2W, a2b, MOD);
    k_msgr<<<dim3(128), dim3(256), 0, stream>>>(V, Z, WTG, smb1, smb2, MOD, Vbuf);

    for (int l = 0; l < 3; ++l) {
        const unsigned short* Wl = WTG + (4 + l * 6) * 16384;
        k_tab<<<dim3(128), dim3(256), 0, stream>>>(Vbuf, Wl, Wl + 2 * 16384, msgb1 + l * 128, TAf, TBb);
        k_edge3<<<dim3(4096), dim3(256), 0, stream>>>(E, K, TAf, TBb, Wl + 16384, Sb);
        int fin = (l == 2);
        k_token<<<dim3(128), dim3(256), 0, stream>>>(
            Sb, Vbuf, Wl + 3 * 16384, msgb2 + l * 128,
            Wl + 4 * 16384, fb1 + l * 128, Wl + 5 * 16384, fb2 + l * 128,
            WTG + 3 * 16384,
            MOD + 1024 + l * 1024, MOD + 4096 + l * 1024,
            fin ? (float*)d_out : Vbuf, fin);
    }
}

// Round 4
// 222.806 us; speedup vs baseline: 1.2825x; 1.2151x over previous
//
#include <hip/hip_runtime.h>
#include <hip/hip_bf16.h>

#define DEV static __device__ __forceinline__

typedef __bf16 bf16x8 __attribute__((ext_vector_type(8)));
typedef unsigned short u16x8 __attribute__((ext_vector_type(8)));
typedef float f32x4 __attribute__((ext_vector_type(4)));

#if __has_builtin(__builtin_amdgcn_exp2f)
#define EXP2F(x) __builtin_amdgcn_exp2f(x)
#else
#define EXP2F(x) exp2f(x)
#endif
#if __has_builtin(__builtin_amdgcn_rcpf)
#define RCPF(x) __builtin_amdgcn_rcpf(x)
#else
#define RCPF(x) (1.0f / (x))
#endif

// ---------- helpers ----------

DEV unsigned short f2bfh(float f) {
    return __builtin_bit_cast(unsigned short, (__bf16)f);   // v_cvt (RNE on gfx950)
}

// gelu(x) = x * sigmoid(1.5957691*(x + 0.044715 x^3))  [tanh-approx, matches jax.nn.gelu]
// exp(-1.5957691*u) = exp2(-(2.3022082*x + 0.10294324*x^3)); 1/(1+e) via v_rcp (~1 ulp)
DEV float gelu_f(float x) {
    float x2 = x * x;
    float t  = __builtin_fmaf(-0.10294324f, x2, -2.3022082f);
    float e  = EXP2F(x * t);
    return x * RCPF(1.0f + e);
}

DEV f32x4 mfma16(bf16x8 a, bf16x8 b, f32x4 c) {
    return __builtin_amdgcn_mfma_f32_16x16x32_bf16(a, b, c, 0, 0, 0);
}

DEV bf16x8 cvt8(float4 x, float4 y) {
    bf16x8 r;
    r[0] = (__bf16)x.x; r[1] = (__bf16)x.y; r[2] = (__bf16)x.z; r[3] = (__bf16)x.w;
    r[4] = (__bf16)y.x; r[5] = (__bf16)y.y; r[6] = (__bf16)y.z; r[7] = (__bf16)y.w;
    return r;
}

// load 8 consecutive f32 (16B-aligned) -> bf16x8
DEV bf16x8 aload_f32(const float* p) {
    float4 x = *(const float4*)p;
    float4 y = *(const float4*)(p + 4);
    return cvt8(x, y);
}

// B-fragment read from LDS WT[n][k] (stride 136 u16), col = n, koff = k start (mult of 8)
DEV bf16x8 bload(const unsigned short* WT, int col, int koff) {
    return __builtin_bit_cast(bf16x8, *(const u16x8*)(WT + col * 136 + koff));
}

// copy pre-transposed bf16 weight [128n][128k] from global into LDS WT[n*136+k]
DEV void stage_wt(unsigned short* WT, const unsigned short* src, int tid, int nthr) {
    for (int i = tid; i < 2048; i += nthr) {
        int n = i >> 4, k0 = (i & 15) << 3;
        *(u16x8*)(WT + n * 136 + k0) = *(const u16x8*)(src + n * 128 + k0);
    }
}

// ---------- weight pre-transpose: f32 [128k][128n] -> bf16 [128n][128k] ----------
// 22 matrices of 128x128: 0 smW1(V-half) 1 smW1(Z-half) 2 smW2 3 proj,
// then per layer l: 4+6l+{0:W1a,1:W1b,2:W1c,3:msgW2,4:ffnW1,5:ffnW2}
__global__ __launch_bounds__(256) void k_wconv(
    const float* __restrict__ smW1, const float* __restrict__ smW2,
    const float* __restrict__ projW, const float* __restrict__ msgW1,
    const float* __restrict__ msgW2, const float* __restrict__ ffnW1,
    const float* __restrict__ ffnW2, unsigned short* __restrict__ WTG)
{
    int m = blockIdx.x >> 3;
    int chunk = blockIdx.x & 7;
    const float* src;
    if (m == 0) src = smW1;
    else if (m == 1) src = smW1 + 16384;
    else if (m == 2) src = smW2;
    else if (m == 3) src = projW;
    else {
        int mm = m - 4; int l = mm / 6; int j = mm % 6;
        if (j < 3)      src = msgW1 + l * 49152 + j * 16384;
        else if (j == 3) src = msgW2 + l * 16384;
        else if (j == 4) src = ffnW1 + l * 16384;
        else             src = ffnW2 + l * 16384;
    }
    unsigned short* dst = WTG + m * 16384;
    int s0 = chunk * 2048 + threadIdx.x * 8;   // flat src index, k = s0>>7, n = s0&127
    int k = s0 >> 7, n = s0 & 127;
    float4 x = *(const float4*)(src + s0);
    float4 y = *(const float4*)(src + s0 + 4);
    dst[(n + 0) * 128 + k] = f2bfh(x.x);
    dst[(n + 1) * 128 + k] = f2bfh(x.y);
    dst[(n + 2) * 128 + k] = f2bfh(x.z);
    dst[(n + 3) * 128 + k] = f2bfh(x.w);
    dst[(n + 4) * 128 + k] = f2bfh(y.x);
    dst[(n + 5) * 128 + k] = f2bfh(y.y);
    dst[(n + 6) * 128 + k] = f2bfh(y.z);
    dst[(n + 7) * 128 + k] = f2bfh(y.w);
}

// ---------- time features + all adaLN modulation vectors ----------
// MOD layout (f32): [0,1024) sm: b*256+c ; [1024,4096) ada1: (l*4+b)*256+c ; [4096,7168) ada2
__global__ __launch_bounds__(256) void k_prep(
    const float* __restrict__ t,
    const float* __restrict__ smadaW, const float* __restrict__ smadab,
    const float* __restrict__ a1W, const float* __restrict__ a1b,
    const float* __restrict__ a2W, const float* __restrict__ a2b,
    float* __restrict__ MOD)
{
    __shared__ float tf[4][128];
    int tid = threadIdx.x;
    {
        int b = tid >> 6, i = tid & 63;
        float wn = __expf(-(float)i * (9.210340371976184f / 64.0f)); // 10000^(-2i/128)
        float ph = t[b] * wn;
        tf[b][2 * i]     = sinf(ph);
        tf[b][2 * i + 1] = cosf(ph);
    }
    __syncthreads();
    int o = blockIdx.x * 256 + tid;   // 0..7167
    int b, c;
    const float* W; const float* bias; float* out;
    if (o < 1024) {
        b = o >> 8; c = o & 255; W = smadaW; bias = smadab; out = MOD + o;
    } else if (o < 4096) {
        int oo = o - 1024; int lb = oo >> 8; int l = lb >> 2;
        b = lb & 3; c = oo & 255;
        W = a1W + l * 32768; bias = a1b + l * 256; out = MOD + o;
    } else {
        int oo = o - 4096; int lb = oo >> 8; int l = lb >> 2;
        b = lb & 3; c = oo & 255;
        W = a2W + l * 32768; bias = a2b + l * 256; out = MOD + 4096 + oo;
    }
    float s = bias[c];
    const float* tfb = tf[b];
    #pragma unroll 8
    for (int k = 0; k < 128; ++k) s += tfb[k] * W[k * 256 + c];
    *out = s;
}

// ---------- sequence messenger MLP + adaLN -> Vbuf ----------
__global__ __launch_bounds__(256) void k_msgr(
    const float* __restrict__ V, const float* __restrict__ Z,
    const unsigned short* __restrict__ WTG,
    const float* __restrict__ smb1, const float* __restrict__ smb2,
    const float* __restrict__ MOD, float* __restrict__ Vout)
{
    __shared__ __align__(16) unsigned short WT[128 * 136];
    __shared__ __align__(16) float XB[64 * 132];
    const int tid = threadIdx.x;
    const int w = tid >> 6, l = tid & 63, lr = l & 15, lg = l >> 4;
    const int tok0 = blockIdx.x * 64;
    const int batch = tok0 >> 11;
    const int rowA = tok0 + w * 16 + lr;

    f32x4 acc[8] = {};
    for (int kh = 0; kh < 2; ++kh) {
        __syncthreads();
        stage_wt(WT, WTG + kh * 16384, tid, 256);
        __syncthreads();
        const float* A = (kh == 0) ? V : Z;
        #pragma unroll
        for (int ks = 0; ks < 4; ++ks) {
            bf16x8 a = aload_f32(A + rowA * 128 + ks * 32 + lg * 8);
            #pragma unroll
            for (int c = 0; c < 8; ++c)
                acc[c] = mfma16(a, bload(WT, c * 16 + lr, ks * 32 + lg * 8), acc[c]);
        }
    }
    // h1 = gelu(acc + b1) -> XB (transposed through LDS)
    #pragma unroll
    for (int c = 0; c < 8; ++c) {
        int col = c * 16 + lr;
        float b1v = smb1[col];
        #pragma unroll
        for (int j = 0; j < 4; ++j)
            XB[(w * 16 + lg * 4 + j) * 132 + col] = gelu_f(acc[c][j] + b1v);
    }
    __syncthreads();
    stage_wt(WT, WTG + 2 * 16384, tid, 256);
    __syncthreads();
    f32x4 acc2[8] = {};
    #pragma unroll
    for (int ks = 0; ks < 4; ++ks) {
        bf16x8 a = aload_f32(XB + (w * 16 + lr) * 132 + ks * 32 + lg * 8);
        #pragma unroll
        for (int c = 0; c < 8; ++c)
            acc2[c] = mfma16(a, bload(WT, c * 16 + lr, ks * 32 + lg * 8), acc2[c]);
    }
    const float* MODp = MOD + batch * 256;
    #pragma unroll
    for (int j = 0; j < 4; ++j) {
        int row = tok0 + w * 16 + lg * 4 + j;
        float xv[8], s1 = 0.f, s2 = 0.f;
        #pragma unroll
        for (int c = 0; c < 8; ++c) {
            int col = c * 16 + lr;
            float x = acc2[c][j] + smb2[col] + V[row * 128 + col];
            xv[c] = x; s1 += x; s2 += x * x;
        }
        #pragma unroll
        for (int m = 1; m <= 8; m <<= 1) { s1 += __shfl_xor(s1, m); s2 += __shfl_xor(s2, m); }
        float mu = s1 * (1.0f / 128.0f);
        float var = s2 * (1.0f / 128.0f) - mu * mu;
        float rs = rsqrtf(var + 1e-5f);
        #pragma unroll
        for (int c = 0; c < 8; ++c) {
            int col = c * 16 + lr;
            Vout[row * 128 + col] = (xv[c] - mu) * rs * (1.0f + MODp[col]) + MODp[128 + col];
        }
    }
}

// ---------- per-layer: TA = V@W1a + b1 (f32), TB = V@W1c (f32) ----------
__global__ __launch_bounds__(256) void k_tab(
    const float* __restrict__ Vb, const unsigned short* __restrict__ WTa,
    const unsigned short* __restrict__ WTc, const float* __restrict__ b1,
    float* __restrict__ TAf, float* __restrict__ TBf)
{
    __shared__ __align__(16) unsigned short WT[128 * 136];
    const int tid = threadIdx.x;
    const int w = tid >> 6, l = tid & 63, lr = l & 15, lg = l >> 4;
    const int tok0 = blockIdx.x * 64;
    const int rowA = tok0 + w * 16 + lr;

    stage_wt(WT, WTa, tid, 256);
    __syncthreads();
    f32x4 acc[8] = {};
    #pragma unroll
    for (int ks = 0; ks < 4; ++ks) {
        bf16x8 a = aload_f32(Vb + rowA * 128 + ks * 32 + lg * 8);
        #pragma unroll
        for (int c = 0; c < 8; ++c)
            acc[c] = mfma16(a, bload(WT, c * 16 + lr, ks * 32 + lg * 8), acc[c]);
    }
    #pragma unroll
    for (int c = 0; c < 8; ++c) {
        int col = c * 16 + lr;
        float b1v = b1[col];
        #pragma unroll
        for (int j = 0; j < 4; ++j) {
            int row = tok0 + w * 16 + lg * 4 + j;
            TAf[row * 128 + col] = acc[c][j] + b1v;
        }
    }
    __syncthreads();
    stage_wt(WT, WTc, tid, 256);
    __syncthreads();
    f32x4 acc2[8] = {};
    #pragma unroll
    for (int ks = 0; ks < 4; ++ks) {
        bf16x8 a = aload_f32(Vb + rowA * 128 + ks * 32 + lg * 8);
        #pragma unroll
        for (int c = 0; c < 8; ++c)
            acc2[c] = mfma16(a, bload(WT, c * 16 + lr, ks * 32 + lg * 8), acc2[c]);
    }
    #pragma unroll
    for (int c = 0; c < 8; ++c) {
        int col = c * 16 + lr;
        #pragma unroll
        for (int j = 0; j < 4; ++j) {
            int row = tok0 + w * 16 + lg * 4 + j;
            TBf[row * 128 + col] = acc2[c][j];
        }
    }
}

// ---------- per-layer edge kernel v4 ----------
// Block 256 thr / 4 waves / 2 tokens; wave = (token, col-half). W1b in LDS (bload),
// E consumed per-lane from global (f32 -> cvt_pk), TB gathered per-lane (f32 scalars).
// Per-m structure keeps live VGPRs ~100 so nothing gets sunk back to memory.
__global__ __launch_bounds__(256, 4) void k_edge4(
    const float* __restrict__ E,            // f32 [8192][30][128]
    const int* __restrict__ Kidx,           // [8192][30]
    const float* __restrict__ TAf,          // f32 [8192][128]
    const float* __restrict__ TBf,          // f32 [8192][128]
    const unsigned short* __restrict__ WTb, // bf16 [128n][128k]
    float* __restrict__ S)                  // f32 [8192][128]
{
    __shared__ __align__(16) unsigned short WT[128 * 136];
    const int tid = threadIdx.x;
    const int w = tid >> 6, l = tid & 63, lr = l & 15, lg = l >> 4;
    const int nh = w & 1;
    const int tok = blockIdx.x * 2 + (w >> 1);
    const int bbase = (tok >> 11) << 11;

    // neighbor indices for this lane's epilogue rows (issue first: HBM latency)
    const int* Kp = Kidx + tok * 30;
    int nb[2][4];
    #pragma unroll
    for (int m = 0; m < 2; ++m)
        #pragma unroll
        for (int j = 0; j < 4; ++j) {
            int r = m * 16 + lg * 4 + j;
            nb[m][j] = (r < 30) ? Kp[r] : 0;
        }
    // per-token A addend
    float ta[4];
    #pragma unroll
    for (int n = 0; n < 4; ++n) ta[n] = TAf[tok * 128 + nh * 64 + n * 16 + lr];

    stage_wt(WT, WTb, tid, 256);
    __syncthreads();

    float sacc[4] = {0.f, 0.f, 0.f, 0.f};
    #pragma unroll
    for (int m = 0; m < 2; ++m) {
        // E fragment raw loads (row er, 8 floats per ks)
        int er = m * 16 + lr; if (er > 29) er = 29;
        const float* ep = E + (size_t)tok * 3840 + er * 128 + lg * 8;
        float4 eraw[4][2];
        #pragma unroll
        for (int ks = 0; ks < 4; ++ks) {
            eraw[ks][0] = *(const float4*)(ep + ks * 32);
            eraw[ks][1] = *(const float4*)(ep + ks * 32 + 4);
        }
        // TB gathers for this m (latency hides under cvt+MFMA below)
        float tb[4][4];
        #pragma unroll
        for (int j = 0; j < 4; ++j) {
            const float* tp = TBf + (size_t)(bbase + nb[m][j]) * 128 + nh * 64 + lr;
            #pragma unroll
            for (int n = 0; n < 4; ++n) tb[j][n] = tp[n * 16];
        }
        // MFMA over K=128, N=64 (4 tiles)
        f32x4 acc[4] = {};
        #pragma unroll
        for (int ks = 0; ks < 4; ++ks) {
            bf16x8 a = cvt8(eraw[ks][0], eraw[ks][1]);
            #pragma unroll
            for (int n = 0; n < 4; ++n)
                acc[n] = mfma16(a, bload(WT, nh * 64 + n * 16 + lr, ks * 32 + lg * 8), acc[n]);
        }
        // epilogue: gelu(acc + ta + tb) summed over rows
        #pragma unroll
        for (int n = 0; n < 4; ++n)
            #pragma unroll
            for (int j = 0; j < 4; ++j) {
                int r = m * 16 + lg * 4 + j;
                if (r < 30)
                    sacc[n] += gelu_f(acc[n][j] + ta[n] + tb[j][n]);
            }
    }
    #pragma unroll
    for (int n = 0; n < 4; ++n) {
        sacc[n] += __shfl_xor(sacc[n], 16);
        sacc[n] += __shfl_xor(sacc[n], 32);
    }
    if (l < 16) {
        #pragma unroll
        for (int n = 0; n < 4; ++n)
            S[tok * 128 + nh * 64 + n * 16 + l] = sacc[n];
    }
}

// ---------- per-layer token kernel: dV/W2, adaLN, FFN, adaLN (+ optional proj) ----------
__global__ __launch_bounds__(256) void k_token(
    const float* __restrict__ Sb, const float* __restrict__ Vb,
    const unsigned short* __restrict__ WTW2, const float* __restrict__ b2,
    const unsigned short* __restrict__ WTF1, const float* __restrict__ fb1,
    const unsigned short* __restrict__ WTF2, const float* __restrict__ fb2,
    const unsigned short* __restrict__ WTP,
    const float* __restrict__ MOD1, const float* __restrict__ MOD2,
    float* __restrict__ Vout, int final_)
{
    __shared__ __align__(16) unsigned short WT[128 * 136];
    __shared__ __align__(16) float XB[64 * 132];
    const int tid = threadIdx.x;
    const int w = tid >> 6, l = tid & 63, lr = l & 15, lg = l >> 4;
    const int tok0 = blockIdx.x * 64;
    const int batch = tok0 >> 11;
    const int rloc = w * 16 + lr;

    stage_wt(WT, WTW2, tid, 256);
    __syncthreads();
    f32x4 acc[8] = {};
    #pragma unroll
    for (int ks = 0; ks < 4; ++ks) {
        bf16x8 a = aload_f32(Sb + (tok0 + rloc) * 128 + ks * 32 + lg * 8);
        #pragma unroll
        for (int c = 0; c < 8; ++c)
            acc[c] = mfma16(a, bload(WT, c * 16 + lr, ks * 32 + lg * 8), acc[c]);
    }
    const float* M1 = MOD1 + batch * 256;
    const float* M2 = MOD2 + batch * 256;
    float vp[8][4];
    #pragma unroll
    for (int j = 0; j < 4; ++j) {
        int row = tok0 + w * 16 + lg * 4 + j;
        float xv[8], s1 = 0.f, s2 = 0.f;
        #pragma unroll
        for (int c = 0; c < 8; ++c) {
            int col = c * 16 + lr;
            float x = acc[c][j] * (1.0f / 30.0f) + b2[col] + Vb[row * 128 + col];
            xv[c] = x; s1 += x; s2 += x * x;
        }
        #pragma unroll
        for (int m = 1; m <= 8; m <<= 1) { s1 += __shfl_xor(s1, m); s2 += __shfl_xor(s2, m); }
        float mu = s1 * (1.0f / 128.0f);
        float var = s2 * (1.0f / 128.0f) - mu * mu;
        float rs = rsqrtf(var + 1e-5f);
        #pragma unroll
        for (int c = 0; c < 8; ++c) {
            int col = c * 16 + lr;
            vp[c][j] = (xv[c] - mu) * rs * (1.0f + M1[col]) + M1[128 + col];
        }
    }
    __syncthreads();
    #pragma unroll
    for (int c = 0; c < 8; ++c)
        #pragma unroll
        for (int j = 0; j < 4; ++j)
            XB[(w * 16 + lg * 4 + j) * 132 + c * 16 + lr] = vp[c][j];
    stage_wt(WT, WTF1, tid, 256);
    __syncthreads();
    f32x4 accB[8] = {};
    #pragma unroll
    for (int ks = 0; ks < 4; ++ks) {
        bf16x8 a = aload_f32(XB + rloc * 132 + ks * 32 + lg * 8);
        #pragma unroll
        for (int c = 0; c < 8; ++c)
            accB[c] = mfma16(a, bload(WT, c * 16 + lr, ks * 32 + lg * 8), accB[c]);
    }
    __syncthreads();
    #pragma unroll
    for (int c = 0; c < 8; ++c) {
        int col = c * 16 + lr;
        float bv = fb1[col];
        #pragma unroll
        for (int j = 0; j < 4; ++j)
            XB[(w * 16 + lg * 4 + j) * 132 + col] = gelu_f(accB[c][j] + bv);
    }
    stage_wt(WT, WTF2, tid, 256);
    __syncthreads();
    f32x4 accC[8] = {};
    #pragma unroll
    for (int ks = 0; ks < 4; ++ks) {
        bf16x8 a = aload_f32(XB + rloc * 132 + ks * 32 + lg * 8);
        #pragma unroll
        for (int c = 0; c < 8; ++c)
            accC[c] = mfma16(a, bload(WT, c * 16 + lr, ks * 32 + lg * 8), accC[c]);
    }
    float v2[8][4];
    #pragma unroll
    for (int j = 0; j < 4; ++j) {
        float xv[8], s1 = 0.f, s2 = 0.f;
        #pragma unroll
        for (int c = 0; c < 8; ++c) {
            int col = c * 16 + lr;
            float x = accC[c][j] + fb2[col] + vp[c][j];
            xv[c] = x; s1 += x; s2 += x * x;
        }
        #pragma unroll
        for (int m = 1; m <= 8; m <<= 1) { s1 += __shfl_xor(s1, m); s2 += __shfl_xor(s2, m); }
        float mu = s1 * (1.0f / 128.0f);
        float var = s2 * (1.0f / 128.0f) - mu * mu;
        float rs = rsqrtf(var + 1e-5f);
        #pragma unroll
        for (int c = 0; c < 8; ++c) {
            int col = c * 16 + lr;
            v2[c][j] = (xv[c] - mu) * rs * (1.0f + M2[col]) + M2[128 + col];
        }
    }
    if (!final_) {
        #pragma unroll
        for (int c = 0; c < 8; ++c)
            #pragma unroll
            for (int j = 0; j < 4; ++j)
                Vout[(tok0 + w * 16 + lg * 4 + j) * 128 + c * 16 + lr] = v2[c][j];
    } else {
        __syncthreads();
        #pragma unroll
        for (int c = 0; c < 8; ++c)
            #pragma unroll
            for (int j = 0; j < 4; ++j)
                XB[(w * 16 + lg * 4 + j) * 132 + c * 16 + lr] = v2[c][j];
        stage_wt(WT, WTP, tid, 256);
        __syncthreads();
        f32x4 accD[8] = {};
        #pragma unroll
        for (int ks = 0; ks < 4; ++ks) {
            bf16x8 a = aload_f32(XB + rloc * 132 + ks * 32 + lg * 8);
            #pragma unroll
            for (int c = 0; c < 8; ++c)
                accD[c] = mfma16(a, bload(WT, c * 16 + lr, ks * 32 + lg * 8), accD[c]);
        }
        #pragma unroll
        for (int c = 0; c < 8; ++c)
            #pragma unroll
            for (int j = 0; j < 4; ++j)
                Vout[(tok0 + w * 16 + lg * 4 + j) * 128 + c * 16 + lr] = accD[c][j];
    }
}

// ---------- host ----------

extern "C" void kernel_launch(void* const* d_in, const int* in_sizes, int n_in,
                              void* d_out, int out_size, void* d_ws, size_t ws_size,
                              hipStream_t stream)
{
    const float* V     = (const float*)d_in[0];
    const float* E     = (const float*)d_in[1];
    const int*   K     = (const int*)d_in[2];
    const float* Z     = (const float*)d_in[3];
    const float* t     = (const float*)d_in[4];
    // d_in[5] = edge_mask (all true in this problem; msg mask is identity)
    const float* smW1   = (const float*)d_in[6];
    const float* smb1   = (const float*)d_in[7];
    const float* smW2   = (const float*)d_in[8];
    const float* smb2   = (const float*)d_in[9];
    const float* smadaW = (const float*)d_in[10];
    const float* smadab = (const float*)d_in[11];
    const float* msgW1  = (const float*)d_in[12];
    const float* msgb1  = (const float*)d_in[13];
    const float* msgW2  = (const float*)d_in[14];
    const float* msgb2  = (const float*)d_in[15];
    const float* a1W    = (const float*)d_in[16];
    const float* a1b    = (const float*)d_in[17];
    const float* fW1    = (const float*)d_in[18];
    const float* fb1    = (const float*)d_in[19];
    const float* fW2    = (const float*)d_in[20];
    const float* fb2    = (const float*)d_in[21];
    const float* a2W    = (const float*)d_in[22];
    const float* a2b    = (const float*)d_in[23];
    const float* projW  = (const float*)d_in[24];

    float* Vbuf = (float*)d_ws;                  // 8192*128 f32
    float* TAf  = Vbuf + 8192 * 128;             // 8192*128 f32
    float* TBf  = TAf + 8192 * 128;              // 8192*128 f32
    float* Sb   = TBf + 8192 * 128;              // 8192*128 f32
    float* MOD  = Sb + 8192 * 128;               // 7168 f32
    unsigned short* WTG = (unsigned short*)(MOD + 7168);   // 22*16384 u16

    k_wconv<<<dim3(176), dim3(256), 0, stream>>>(smW1, smW2, projW, msgW1, msgW2, fW1, fW2, WTG);
    k_prep<<<dim3(28), dim3(256), 0, stream>>>(t, smadaW, smadab, a1W, a1b, a2W, a2b, MOD);
    k_msgr<<<dim3(128), dim3(256), 0, stream>>>(V, Z, WTG, smb1, smb2, MOD, Vbuf);

    for (int l = 0; l < 3; ++l) {
        const unsigned short* Wl = WTG + (4 + l * 6) * 16384;
        k_tab<<<dim3(128), dim3(256), 0, stream>>>(Vbuf, Wl, Wl + 2 * 16384, msgb1 + l * 128, TAf, TBf);
        k_edge4<<<dim3(4096), dim3(256), 0, stream>>>(E, K, TAf, TBf, Wl + 16384, Sb);
        int fin = (l == 2);
        k_token<<<dim3(128), dim3(256), 0, stream>>>(
            Sb, Vbuf, Wl + 3 * 16384, msgb2 + l * 128,
            Wl + 4 * 16384, fb1 + l * 128, Wl + 5 * 16384, fb2 + l * 128,
            WTG + 3 * 16384,
            MOD + 1024 + l * 1024, MOD + 4096 + l * 1024,
            fin ? (float*)d_out : Vbuf, fin);
    }
}

// Round 5
// 212.547 us; speedup vs baseline: 1.3444x; 1.0483x over previous
//
#include <hip/hip_runtime.h>
#include <hip/hip_bf16.h>

#define DEV static __device__ __forceinline__

typedef __bf16 bf16x8 __attribute__((ext_vector_type(8)));
typedef unsigned short u16x8 __attribute__((ext_vector_type(8)));
typedef unsigned short u16x4 __attribute__((ext_vector_type(4)));
typedef float f32x4 __attribute__((ext_vector_type(4)));

#if __has_builtin(__builtin_amdgcn_exp2f)
#define EXP2F(x) __builtin_amdgcn_exp2f(x)
#else
#define EXP2F(x) exp2f(x)
#endif
#if __has_builtin(__builtin_amdgcn_rcpf)
#define RCPF(x) __builtin_amdgcn_rcpf(x)
#else
#define RCPF(x) (1.0f / (x))
#endif

// ---------- helpers ----------

DEV unsigned short f2bfh(float f) {
    return __builtin_bit_cast(unsigned short, (__bf16)f);   // v_cvt (RNE on gfx950)
}

// gelu(x) = x * sigmoid(1.5957691*(x + 0.044715 x^3))  [tanh-approx, matches jax.nn.gelu]
DEV float gelu_f(float x) {
    float x2 = x * x;
    float t  = __builtin_fmaf(-0.10294324f, x2, -2.3022082f);
    float e  = EXP2F(x * t);
    return x * RCPF(1.0f + e);
}

DEV f32x4 mfma16(bf16x8 a, bf16x8 b, f32x4 c) {
    return __builtin_amdgcn_mfma_f32_16x16x32_bf16(a, b, c, 0, 0, 0);
}

DEV bf16x8 cvt8(float4 x, float4 y) {
    bf16x8 r;
    r[0] = (__bf16)x.x; r[1] = (__bf16)x.y; r[2] = (__bf16)x.z; r[3] = (__bf16)x.w;
    r[4] = (__bf16)y.x; r[5] = (__bf16)y.y; r[6] = (__bf16)y.z; r[7] = (__bf16)y.w;
    return r;
}

// load 8 consecutive f32 (16B-aligned) -> bf16x8
DEV bf16x8 aload_f32(const float* p) {
    float4 x = *(const float4*)p;
    float4 y = *(const float4*)(p + 4);
    return cvt8(x, y);
}

// B-fragment read from LDS WT[n][k] (stride 136 u16), col = n, koff = k start (mult of 8)
DEV bf16x8 bload(const unsigned short* WT, int col, int koff) {
    return __builtin_bit_cast(bf16x8, *(const u16x8*)(WT + col * 136 + koff));
}

// copy pre-transposed bf16 weight [128n][128k] from global into LDS WT[n*136+k]
DEV void stage_wt(unsigned short* WT, const unsigned short* src, int tid, int nthr) {
    for (int i = tid; i < 2048; i += nthr) {
        int n = i >> 4, k0 = (i & 15) << 3;
        *(u16x8*)(WT + n * 136 + k0) = *(const u16x8*)(src + n * 128 + k0);
    }
}

// ---------- weight pre-transpose: f32 [128k][128n] -> bf16 [128n][128k] ----------
// 22 matrices of 128x128: 0 smW1(V-half) 1 smW1(Z-half) 2 smW2 3 proj,
// then per layer l: 4+6l+{0:W1a,1:W1b,2:W1c,3:msgW2,4:ffnW1,5:ffnW2}
__global__ __launch_bounds__(256) void k_wconv(
    const float* __restrict__ smW1, const float* __restrict__ smW2,
    const float* __restrict__ projW, const float* __restrict__ msgW1,
    const float* __restrict__ msgW2, const float* __restrict__ ffnW1,
    const float* __restrict__ ffnW2, unsigned short* __restrict__ WTG)
{
    int m = blockIdx.x >> 3;
    int chunk = blockIdx.x & 7;
    const float* src;
    if (m == 0) src = smW1;
    else if (m == 1) src = smW1 + 16384;
    else if (m == 2) src = smW2;
    else if (m == 3) src = projW;
    else {
        int mm = m - 4; int l = mm / 6; int j = mm % 6;
        if (j < 3)      src = msgW1 + l * 49152 + j * 16384;
        else if (j == 3) src = msgW2 + l * 16384;
        else if (j == 4) src = ffnW1 + l * 16384;
        else             src = ffnW2 + l * 16384;
    }
    unsigned short* dst = WTG + m * 16384;
    int s0 = chunk * 2048 + threadIdx.x * 8;   // flat src index, k = s0>>7, n = s0&127
    int k = s0 >> 7, n = s0 & 127;
    float4 x = *(const float4*)(src + s0);
    float4 y = *(const float4*)(src + s0 + 4);
    dst[(n + 0) * 128 + k] = f2bfh(x.x);
    dst[(n + 1) * 128 + k] = f2bfh(x.y);
    dst[(n + 2) * 128 + k] = f2bfh(x.z);
    dst[(n + 3) * 128 + k] = f2bfh(x.w);
    dst[(n + 4) * 128 + k] = f2bfh(y.x);
    dst[(n + 5) * 128 + k] = f2bfh(y.y);
    dst[(n + 6) * 128 + k] = f2bfh(y.z);
    dst[(n + 7) * 128 + k] = f2bfh(y.w);
}

// ---------- time features + all adaLN modulation vectors ----------
// MOD layout (f32): [0,1024) sm: b*256+c ; [1024,4096) ada1: (l*4+b)*256+c ; [4096,7168) ada2
__global__ __launch_bounds__(256) void k_prep(
    const float* __restrict__ t,
    const float* __restrict__ smadaW, const float* __restrict__ smadab,
    const float* __restrict__ a1W, const float* __restrict__ a1b,
    const float* __restrict__ a2W, const float* __restrict__ a2b,
    float* __restrict__ MOD)
{
    __shared__ float tf[4][128];
    int tid = threadIdx.x;
    {
        int b = tid >> 6, i = tid & 63;
        float wn = __expf(-(float)i * (9.210340371976184f / 64.0f)); // 10000^(-2i/128)
        float ph = t[b] * wn;
        tf[b][2 * i]     = sinf(ph);
        tf[b][2 * i + 1] = cosf(ph);
    }
    __syncthreads();
    int o = blockIdx.x * 256 + tid;   // 0..7167
    int b, c;
    const float* W; const float* bias; float* out;
    if (o < 1024) {
        b = o >> 8; c = o & 255; W = smadaW; bias = smadab; out = MOD + o;
    } else if (o < 4096) {
        int oo = o - 1024; int lb = oo >> 8; int l = lb >> 2;
        b = lb & 3; c = oo & 255;
        W = a1W + l * 32768; bias = a1b + l * 256; out = MOD + o;
    } else {
        int oo = o - 4096; int lb = oo >> 8; int l = lb >> 2;
        b = lb & 3; c = oo & 255;
        W = a2W + l * 32768; bias = a2b + l * 256; out = MOD + 4096 + oo;
    }
    float s = bias[c];
    const float* tfb = tf[b];
    #pragma unroll 8
    for (int k = 0; k < 128; ++k) s += tfb[k] * W[k * 256 + c];
    *out = s;
}

// ---------- sequence messenger MLP + adaLN -> Vbuf ----------
__global__ __launch_bounds__(256) void k_msgr(
    const float* __restrict__ V, const float* __restrict__ Z,
    const unsigned short* __restrict__ WTG,
    const float* __restrict__ smb1, const float* __restrict__ smb2,
    const float* __restrict__ MOD, float* __restrict__ Vout)
{
    __shared__ __align__(16) unsigned short WT[128 * 136];
    __shared__ __align__(16) float XB[64 * 132];
    const int tid = threadIdx.x;
    const int w = tid >> 6, l = tid & 63, lr = l & 15, lg = l >> 4;
    const int tok0 = blockIdx.x * 64;
    const int batch = tok0 >> 11;
    const int rowA = tok0 + w * 16 + lr;

    f32x4 acc[8] = {};
    for (int kh = 0; kh < 2; ++kh) {
        __syncthreads();
        stage_wt(WT, WTG + kh * 16384, tid, 256);
        __syncthreads();
        const float* A = (kh == 0) ? V : Z;
        #pragma unroll
        for (int ks = 0; ks < 4; ++ks) {
            bf16x8 a = aload_f32(A + rowA * 128 + ks * 32 + lg * 8);
            #pragma unroll
            for (int c = 0; c < 8; ++c)
                acc[c] = mfma16(a, bload(WT, c * 16 + lr, ks * 32 + lg * 8), acc[c]);
        }
    }
    // h1 = gelu(acc + b1) -> XB (transposed through LDS)
    #pragma unroll
    for (int c = 0; c < 8; ++c) {
        int col = c * 16 + lr;
        float b1v = smb1[col];
        #pragma unroll
        for (int j = 0; j < 4; ++j)
            XB[(w * 16 + lg * 4 + j) * 132 + col] = gelu_f(acc[c][j] + b1v);
    }
    __syncthreads();
    stage_wt(WT, WTG + 2 * 16384, tid, 256);
    __syncthreads();
    f32x4 acc2[8] = {};
    #pragma unroll
    for (int ks = 0; ks < 4; ++ks) {
        bf16x8 a = aload_f32(XB + (w * 16 + lr) * 132 + ks * 32 + lg * 8);
        #pragma unroll
        for (int c = 0; c < 8; ++c)
            acc2[c] = mfma16(a, bload(WT, c * 16 + lr, ks * 32 + lg * 8), acc2[c]);
    }
    const float* MODp = MOD + batch * 256;
    #pragma unroll
    for (int j = 0; j < 4; ++j) {
        int row = tok0 + w * 16 + lg * 4 + j;
        float xv[8], s1 = 0.f, s2 = 0.f;
        #pragma unroll
        for (int c = 0; c < 8; ++c) {
            int col = c * 16 + lr;
            float x = acc2[c][j] + smb2[col] + V[row * 128 + col];
            xv[c] = x; s1 += x; s2 += x * x;
        }
        #pragma unroll
        for (int m = 1; m <= 8; m <<= 1) { s1 += __shfl_xor(s1, m); s2 += __shfl_xor(s2, m); }
        float mu = s1 * (1.0f / 128.0f);
        float var = s2 * (1.0f / 128.0f) - mu * mu;
        float rs = rsqrtf(var + 1e-5f);
        #pragma unroll
        for (int c = 0; c < 8; ++c) {
            int col = c * 16 + lr;
            Vout[row * 128 + col] = (xv[c] - mu) * rs * (1.0f + MODp[col]) + MODp[128 + col];
        }
    }
}

// ---------- per-layer: TA = V@W1a + b1 (f32), TB = V@W1c (f32) ----------
__global__ __launch_bounds__(256) void k_tab(
    const float* __restrict__ Vb, const unsigned short* __restrict__ WTa,
    const unsigned short* __restrict__ WTc, const float* __restrict__ b1,
    float* __restrict__ TAf, float* __restrict__ TBf)
{
    __shared__ __align__(16) unsigned short WT[128 * 136];
    const int tid = threadIdx.x;
    const int w = tid >> 6, l = tid & 63, lr = l & 15, lg = l >> 4;
    const int tok0 = blockIdx.x * 64;
    const int rowA = tok0 + w * 16 + lr;

    stage_wt(WT, WTa, tid, 256);
    __syncthreads();
    f32x4 acc[8] = {};
    #pragma unroll
    for (int ks = 0; ks < 4; ++ks) {
        bf16x8 a = aload_f32(Vb + rowA * 128 + ks * 32 + lg * 8);
        #pragma unroll
        for (int c = 0; c < 8; ++c)
            acc[c] = mfma16(a, bload(WT, c * 16 + lr, ks * 32 + lg * 8), acc[c]);
    }
    #pragma unroll
    for (int c = 0; c < 8; ++c) {
        int col = c * 16 + lr;
        float b1v = b1[col];
        #pragma unroll
        for (int j = 0; j < 4; ++j) {
            int row = tok0 + w * 16 + lg * 4 + j;
            TAf[row * 128 + col] = acc[c][j] + b1v;
        }
    }
    __syncthreads();
    stage_wt(WT, WTc, tid, 256);
    __syncthreads();
    f32x4 acc2[8] = {};
    #pragma unroll
    for (int ks = 0; ks < 4; ++ks) {
        bf16x8 a = aload_f32(Vb + rowA * 128 + ks * 32 + lg * 8);
        #pragma unroll
        for (int c = 0; c < 8; ++c)
            acc2[c] = mfma16(a, bload(WT, c * 16 + lr, ks * 32 + lg * 8), acc2[c]);
    }
    #pragma unroll
    for (int c = 0; c < 8; ++c) {
        int col = c * 16 + lr;
        #pragma unroll
        for (int j = 0; j < 4; ++j) {
            int row = tok0 + w * 16 + lg * 4 + j;
            TBf[row * 128 + col] = acc2[c][j];
        }
    }
}

// ---------- per-layer edge kernel v5 ----------
// Block 256 thr / 4 waves / 2 tokens; wave = (token, col-half).
// W1b in LDS (R4) + E staged coalesced f32->bf16 into swizzled LDS (R3) +
// TB gathers for BOTH m-halves hoisted before the barrier (max MLP).
__global__ __launch_bounds__(256, 3) void k_edge5(
    const float* __restrict__ E,            // f32 [8192][30][128]
    const int* __restrict__ Kidx,           // [8192][30]
    const float* __restrict__ TAf,          // f32 [8192][128]
    const float* __restrict__ TBf,          // f32 [8192][128]
    const unsigned short* __restrict__ WTb, // bf16 [128n][128k]
    float* __restrict__ S)                  // f32 [8192][128]
{
    __shared__ __align__(16) unsigned short WT[128 * 136];    // 34816 B
    __shared__ __align__(16) unsigned short EL[2 * 32 * 128]; // 16384 B
    const int tid = threadIdx.x;
    const int w = tid >> 6, l = tid & 63, lr = l & 15, lg = l >> 4;
    const int nh = w & 1;
    const int tl_w = w >> 1;
    const int tokbase = blockIdx.x * 2;
    const int tok = tokbase + tl_w;
    const int bbase = (tok >> 11) << 11;

    // 1) neighbor indices (feed the TB gather addresses)
    const int* Kp = Kidx + tok * 30;
    int nb[2][4];
    #pragma unroll
    for (int m = 0; m < 2; ++m)
        #pragma unroll
        for (int j = 0; j < 4; ++j) {
            int r = m * 16 + lg * 4 + j;
            nb[m][j] = (r < 30) ? Kp[r] : 0;
        }

    // 2) stage E coalesced (f32 -> bf16, swizzled): 2 tok x 30 rows x 32 f4-chunks
    #pragma unroll
    for (int it = 0; it < 8; ++it) {
        int s = it * 256 + tid;
        if (s < 1920) {
            int tl = (s >= 960) ? 1 : 0;
            int rem = s - tl * 960;
            int r = rem >> 5;
            int q = rem & 31;
            float4 x = *(const float4*)(E + ((size_t)(tokbase + tl) * 30 + r) * 128 + q * 4);
            u16x4 pk;
            pk[0] = f2bfh(x.x); pk[1] = f2bfh(x.y); pk[2] = f2bfh(x.z); pk[3] = f2bfh(x.w);
            *(u16x4*)((char*)EL + tl * 8192 + r * 256 + ((q * 8) ^ ((r & 7) << 4))) = pk;
        }
    }
    // 3) weights -> LDS
    stage_wt(WT, WTb, tid, 256);

    // 4) per-token A addend
    float ta[4];
    #pragma unroll
    for (int n = 0; n < 4; ++n) ta[n] = TAf[tok * 128 + nh * 64 + n * 16 + lr];

    // 5) TB gathers for both m-halves (in flight across the barrier + MFMA)
    float tb[2][4][4];
    #pragma unroll
    for (int m = 0; m < 2; ++m)
        #pragma unroll
        for (int j = 0; j < 4; ++j) {
            const float* tp = TBf + (size_t)(bbase + nb[m][j]) * 128 + nh * 64 + lr;
            #pragma unroll
            for (int n = 0; n < 4; ++n) tb[m][j][n] = tp[n * 16];
        }

    __syncthreads();

    // compute: M = 32 rows (2 m-tiles), N = 64 cols (4 tiles), K = 128
    const char* ebase = (const char*)EL + tl_w * 8192;
    float sacc[4] = {0.f, 0.f, 0.f, 0.f};
    #pragma unroll
    for (int m = 0; m < 2; ++m) {
        bf16x8 ar[4];
        #pragma unroll
        for (int ks = 0; ks < 4; ++ks)
            ar[ks] = *(const bf16x8*)(ebase + (m * 16 + lr) * 256 +
                                      (((ks * 32 + lg * 8) * 2) ^ ((lr & 7) << 4)));
        f32x4 acc[4] = {};
        #pragma unroll
        for (int ks = 0; ks < 4; ++ks)
            #pragma unroll
            for (int n = 0; n < 4; ++n)
                acc[n] = mfma16(ar[ks], bload(WT, nh * 64 + n * 16 + lr, ks * 32 + lg * 8), acc[n]);
        #pragma unroll
        for (int n = 0; n < 4; ++n)
            #pragma unroll
            for (int j = 0; j < 4; ++j) {
                int r = m * 16 + lg * 4 + j;
                if (r < 30)
                    sacc[n] += gelu_f(acc[n][j] + ta[n] + tb[m][j][n]);
            }
    }
    #pragma unroll
    for (int n = 0; n < 4; ++n) {
        sacc[n] += __shfl_xor(sacc[n], 16);
        sacc[n] += __shfl_xor(sacc[n], 32);
    }
    if (l < 16) {
        #pragma unroll
        for (int n = 0; n < 4; ++n)
            S[tok * 128 + nh * 64 + n * 16 + l] = sacc[n];
    }
}

// ---------- per-layer token kernel: dV/W2, adaLN, FFN, adaLN (+ optional proj) ----------
__global__ __launch_bounds__(256) void k_token(
    const float* __restrict__ Sb, const float* __restrict__ Vb,
    const unsigned short* __restrict__ WTW2, const float* __restrict__ b2,
    const unsigned short* __restrict__ WTF1, const float* __restrict__ fb1,
    const unsigned short* __restrict__ WTF2, const float* __restrict__ fb2,
    const unsigned short* __restrict__ WTP,
    const float* __restrict__ MOD1, const float* __restrict__ MOD2,
    float* __restrict__ Vout, int final_)
{
    __shared__ __align__(16) unsigned short WT[128 * 136];
    __shared__ __align__(16) float XB[64 * 132];
    const int tid = threadIdx.x;
    const int w = tid >> 6, l = tid & 63, lr = l & 15, lg = l >> 4;
    const int tok0 = blockIdx.x * 64;
    const int batch = tok0 >> 11;
    const int rloc = w * 16 + lr;

    stage_wt(WT, WTW2, tid, 256);
    __syncthreads();
    f32x4 acc[8] = {};
    #pragma unroll
    for (int ks = 0; ks < 4; ++ks) {
        bf16x8 a = aload_f32(Sb + (tok0 + rloc) * 128 + ks * 32 + lg * 8);
        #pragma unroll
        for (int c = 0; c < 8; ++c)
            acc[c] = mfma16(a, bload(WT, c * 16 + lr, ks * 32 + lg * 8), acc[c]);
    }
    const float* M1 = MOD1 + batch * 256;
    const float* M2 = MOD2 + batch * 256;
    float vp[8][4];
    #pragma unroll
    for (int j = 0; j < 4; ++j) {
        int row = tok0 + w * 16 + lg * 4 + j;
        float xv[8], s1 = 0.f, s2 = 0.f;
        #pragma unroll
        for (int c = 0; c < 8; ++c) {
            int col = c * 16 + lr;
            float x = acc[c][j] * (1.0f / 30.0f) + b2[col] + Vb[row * 128 + col];
            xv[c] = x; s1 += x; s2 += x * x;
        }
        #pragma unroll
        for (int m = 1; m <= 8; m <<= 1) { s1 += __shfl_xor(s1, m); s2 += __shfl_xor(s2, m); }
        float mu = s1 * (1.0f / 128.0f);
        float var = s2 * (1.0f / 128.0f) - mu * mu;
        float rs = rsqrtf(var + 1e-5f);
        #pragma unroll
        for (int c = 0; c < 8; ++c) {
            int col = c * 16 + lr;
            vp[c][j] = (xv[c] - mu) * rs * (1.0f + M1[col]) + M1[128 + col];
        }
    }
    __syncthreads();
    #pragma unroll
    for (int c = 0; c < 8; ++c)
        #pragma unroll
        for (int j = 0; j < 4; ++j)
            XB[(w * 16 + lg * 4 + j) * 132 + c * 16 + lr] = vp[c][j];
    stage_wt(WT, WTF1, tid, 256);
    __syncthreads();
    f32x4 accB[8] = {};
    #pragma unroll
    for (int ks = 0; ks < 4; ++ks) {
        bf16x8 a = aload_f32(XB + rloc * 132 + ks * 32 + lg * 8);
        #pragma unroll
        for (int c = 0; c < 8; ++c)
            accB[c] = mfma16(a, bload(WT, c * 16 + lr, ks * 32 + lg * 8), accB[c]);
    }
    __syncthreads();
    #pragma unroll
    for (int c = 0; c < 8; ++c) {
        int col = c * 16 + lr;
        float bv = fb1[col];
        #pragma unroll
        for (int j = 0; j < 4; ++j)
            XB[(w * 16 + lg * 4 + j) * 132 + col] = gelu_f(accB[c][j] + bv);
    }
    stage_wt(WT, WTF2, tid, 256);
    __syncthreads();
    f32x4 accC[8] = {};
    #pragma unroll
    for (int ks = 0; ks < 4; ++ks) {
        bf16x8 a = aload_f32(XB + rloc * 132 + ks * 32 + lg * 8);
        #pragma unroll
        for (int c = 0; c < 8; ++c)
            accC[c] = mfma16(a, bload(WT, c * 16 + lr, ks * 32 + lg * 8), accC[c]);
    }
    float v2[8][4];
    #pragma unroll
    for (int j = 0; j < 4; ++j) {
        float xv[8], s1 = 0.f, s2 = 0.f;
        #pragma unroll
        for (int c = 0; c < 8; ++c) {
            int col = c * 16 + lr;
            float x = accC[c][j] + fb2[col] + vp[c][j];
            xv[c] = x; s1 += x; s2 += x * x;
        }
        #pragma unroll
        for (int m = 1; m <= 8; m <<= 1) { s1 += __shfl_xor(s1, m); s2 += __shfl_xor(s2, m); }
        float mu = s1 * (1.0f / 128.0f);
        float var = s2 * (1.0f / 128.0f) - mu * mu;
        float rs = rsqrtf(var + 1e-5f);
        #pragma unroll
        for (int c = 0; c < 8; ++c) {
            int col = c * 16 + lr;
            v2[c][j] = (xv[c] - mu) * rs * (1.0f + M2[col]) + M2[128 + col];
        }
    }
    if (!final_) {
        #pragma unroll
        for (int c = 0; c < 8; ++c)
            #pragma unroll
            for (int j = 0; j < 4; ++j)
                Vout[(tok0 + w * 16 + lg * 4 + j) * 128 + c * 16 + lr] = v2[c][j];
    } else {
        __syncthreads();
        #pragma unroll
        for (int c = 0; c < 8; ++c)
            #pragma unroll
            for (int j = 0; j < 4; ++j)
                XB[(w * 16 + lg * 4 + j) * 132 + c * 16 + lr] = v2[c][j];
        stage_wt(WT, WTP, tid, 256);
        __syncthreads();
        f32x4 accD[8] = {};
        #pragma unroll
        for (int ks = 0; ks < 4; ++ks) {
            bf16x8 a = aload_f32(XB + rloc * 132 + ks * 32 + lg * 8);
            #pragma unroll
            for (int c = 0; c < 8; ++c)
                accD[c] = mfma16(a, bload(WT, c * 16 + lr, ks * 32 + lg * 8), accD[c]);
        }
        #pragma unroll
        for (int c = 0; c < 8; ++c)
            #pragma unroll
            for (int j = 0; j < 4; ++j)
                Vout[(tok0 + w * 16 + lg * 4 + j) * 128 + c * 16 + lr] = accD[c][j];
    }
}

// ---------- host ----------

extern "C" void kernel_launch(void* const* d_in, const int* in_sizes, int n_in,
                              void* d_out, int out_size, void* d_ws, size_t ws_size,
                              hipStream_t stream)
{
    const float* V     = (const float*)d_in[0];
    const float* E     = (const float*)d_in[1];
    const int*   K     = (const int*)d_in[2];
    const float* Z     = (const float*)d_in[3];
    const float* t     = (const float*)d_in[4];
    // d_in[5] = edge_mask (all true in this problem; msg mask is identity)
    const float* smW1   = (const float*)d_in[6];
    const float* smb1   = (const float*)d_in[7];
    const float* smW2   = (const float*)d_in[8];
    const float* smb2   = (const float*)d_in[9];
    const float* smadaW = (const float*)d_in[10];
    const float* smadab = (const float*)d_in[11];
    const float* msgW1  = (const float*)d_in[12];
    const float* msgb1  = (const float*)d_in[13];
    const float* msgW2  = (const float*)d_in[14];
    const float* msgb2  = (const float*)d_in[15];
    const float* a1W    = (const float*)d_in[16];
    const float* a1b    = (const float*)d_in[17];
    const float* fW1    = (const float*)d_in[18];
    const float* fb1    = (const float*)d_in[19];
    const float* fW2    = (const float*)d_in[20];
    const float* fb2    = (const float*)d_in[21];
    const float* a2W    = (const float*)d_in[22];
    const float* a2b    = (const float*)d_in[23];
    const float* projW  = (const float*)d_in[24];

    float* Vbuf = (float*)d_ws;                  // 8192*128 f32
    float* TAf  = Vbuf + 8192 * 128;             // 8192*128 f32
    float* TBf  = TAf + 8192 * 128;              // 8192*128 f32
    float* Sb   = TBf + 8192 * 128;              // 8192*128 f32
    float* MOD  = Sb + 8192 * 128;               // 7168 f32
    unsigned short* WTG = (unsigned short*)(MOD + 7168);   // 22*16384 u16

    k_wconv<<<dim3(176), dim3(256), 0, stream>>>(smW1, smW2, projW, msgW1, msgW2, fW1, fW2, WTG);
    k_prep<<<dim3(28), dim3(256), 0, stream>>>(t, smadaW, smadab, a1W, a1b, a2W, a2b, MOD);
    k_msgr<<<dim3(128), dim3(256), 0, stream>>>(V, Z, WTG, smb1, smb2, MOD, Vbuf);

    for (int l = 0; l < 3; ++l) {
        const unsigned short* Wl = WTG + (4 + l * 6) * 16384;
        k_tab<<<dim3(128), dim3(256), 0, stream>>>(Vbuf, Wl, Wl + 2 * 16384, msgb1 + l * 128, TAf, TBf);
        k_edge5<<<dim3(4096), dim3(256), 0, stream>>>(E, K, TAf, TBf, Wl + 16384, Sb);
        int fin = (l == 2);
        k_token<<<dim3(128), dim3(256), 0, stream>>>(
            Sb, Vbuf, Wl + 3 * 16384, msgb2 + l * 128,
            Wl + 4 * 16384, fb1 + l * 128, Wl + 5 * 16384, fb2 + l * 128,
            WTG + 3 * 16384,
            MOD + 1024 + l * 1024, MOD + 4096 + l * 1024,
            fin ? (float*)d_out : Vbuf, fin);
    }
}